// Round 1
// baseline (7194.724 us; speedup 1.0000x reference)
//
#include <hip/hip_runtime.h>
#include <math.h>

#define NB 8
#define CDIM 512
#define NT 1024
#define MT 256
#define NHEADS 8
#define DHEAD 64
#define DFFI 2048   // GEGLU inner half

__device__ __forceinline__ float sigmoidf_(float v){ return 1.0f/(1.0f+__expf(-v)); }

// scale_shift[b*1024+o] = silu(emb[b,:]) . w_emb[o,:] + b_emb[o]
__global__ void emb_gemm(const float* __restrict__ emb, const float* __restrict__ w,
                         const float* __restrict__ bias, float* __restrict__ out){
    int idx = blockIdx.x*256 + threadIdx.x;   // 8*1024 total
    int b = idx >> 10, o = idx & 1023;
    const float* e = emb + b*128;
    const float* wr = w + (size_t)o*128;
    float acc = 0.f;
    for (int i=0;i<128;i++){ float ev=e[i]; acc += (ev*sigmoidf_(ev))*wr[i]; }
    out[idx] = acc + bias[o];
}

// GroupNorm stats: one block per (b,group); 16 ch x 1024 contiguous
__global__ void gn_stats(const float* __restrict__ x, float* __restrict__ stats){
    int bg = blockIdx.x;               // b*32+g
    const float* base = x + (size_t)bg*16*NT;
    float s=0.f, sq=0.f;
    for (int i=threadIdx.x; i<16*NT; i+=256){ float v = base[i]; s+=v; sq+=v*v; }
    __shared__ float rs[256], rq[256];
    rs[threadIdx.x]=s; rq[threadIdx.x]=sq; __syncthreads();
    for (int st=128; st>0; st>>=1){
        if (threadIdx.x<st){ rs[threadIdx.x]+=rs[threadIdx.x+st]; rq[threadIdx.x]+=rq[threadIdx.x+st]; }
        __syncthreads();
    }
    if (threadIdx.x==0){
        float mu = rs[0]/(16.f*NT);
        float var = rq[0]/(16.f*NT) - mu*mu;
        stats[2*bg] = mu; stats[2*bg+1] = rsqrtf(var + 1e-6f);
    }
}

// act_t[b,n,c] = silu( GN(x)[b,c,n]*(1+scale[b,c]) + shift[b,c] )  (transposed to token-major)
__global__ void mod_act(const float* __restrict__ x, const float* __restrict__ stats,
                        const float* __restrict__ gg, const float* __restrict__ gb,
                        const float* __restrict__ ss, float* __restrict__ act_t){
    __shared__ float tile[32][33];
    int n0 = blockIdx.x*32, c0 = blockIdx.y*32, b = blockIdx.z;
    int tx = threadIdx.x, ty = threadIdx.y;
    #pragma unroll
    for (int k=0;k<4;k++){
        int c = c0 + ty + k*8;
        tile[ty+k*8][tx] = x[((size_t)(b*CDIM+c))*NT + n0 + tx];
    }
    __syncthreads();
    #pragma unroll
    for (int k=0;k<4;k++){
        int c = c0 + tx, n = n0 + ty + k*8;
        float raw = tile[tx][ty+k*8];
        int gi = b*32 + (c>>4);
        float v = (raw - stats[2*gi]) * stats[2*gi+1] * gg[c] + gb[c];
        v = v * (1.f + ss[b*1024 + c]) + ss[b*1024 + 512 + c];
        act_t[((size_t)(b*NT+n))*CDIM + c] = v * sigmoidf_(v);
    }
}

// LayerNorm over rows of 512
__global__ void ln_rows(const float* __restrict__ in, const float* __restrict__ g,
                        const float* __restrict__ bta, float* __restrict__ out){
    int row = blockIdx.x;
    const float* base = in + (size_t)row*CDIM;
    int t = threadIdx.x;
    float v0 = base[t], v1 = base[t+256];
    __shared__ float rs[256], rq[256];
    rs[t]=v0+v1; rq[t]=v0*v0+v1*v1; __syncthreads();
    for (int st=128; st>0; st>>=1){
        if (t<st){ rs[t]+=rs[t+st]; rq[t]+=rq[t+st]; }
        __syncthreads();
    }
    float mu = rs[0]*(1.f/512.f);
    float var = rq[0]*(1.f/512.f) - mu*mu;
    float rstd = rsqrtf(var + 1e-5f);
    out[(size_t)row*CDIM + t]     = (v0-mu)*rstd*g[t]+bta[t];
    out[(size_t)row*CDIM + t+256] = (v1-mu)*rstd*g[t+256]+bta[t+256];
}

// out[r,o] = sum_k A[r,k]*W[o,k] (+bias[o]) (+res). rows%64==0, O%64==0, K%16==0
// resmode: 0 none, 1 res[r*O+o], 2 res is x-layout [B,512,1024]: res[(b*512+o)*1024+n], r=b*1024+n
__global__ __launch_bounds__(256) void gemm_tn(
        const float* __restrict__ A, const float* __restrict__ W,
        const float* __restrict__ bias, const float* __restrict__ res,
        float* __restrict__ out, int K, int O, int resmode){
    __shared__ float As[64][17], Bs[64][17];
    int r0 = blockIdx.x*64, o0 = blockIdx.y*64;
    int tid = threadIdx.x;
    int tx = tid & 15, ty = tid >> 4;
    int lr = tid >> 2, ls = tid & 3;
    float acc[4][4] = {};
    for (int k0 = 0; k0 < K; k0 += 16){
        float4 av = *(const float4*)(A + (size_t)(r0+lr)*K + k0 + ls*4);
        float4 bv = *(const float4*)(W + (size_t)(o0+lr)*K + k0 + ls*4);
        As[lr][ls*4+0]=av.x; As[lr][ls*4+1]=av.y; As[lr][ls*4+2]=av.z; As[lr][ls*4+3]=av.w;
        Bs[lr][ls*4+0]=bv.x; Bs[lr][ls*4+1]=bv.y; Bs[lr][ls*4+2]=bv.z; Bs[lr][ls*4+3]=bv.w;
        __syncthreads();
        #pragma unroll
        for (int kk=0;kk<16;kk++){
            float a[4], bb[4];
            #pragma unroll
            for (int i=0;i<4;i++) a[i]  = As[ty*4+i][kk];
            #pragma unroll
            for (int j=0;j<4;j++) bb[j] = Bs[tx*4+j][kk];
            #pragma unroll
            for (int i=0;i<4;i++)
                #pragma unroll
                for (int j=0;j<4;j++) acc[i][j] += a[i]*bb[j];
        }
        __syncthreads();
    }
    #pragma unroll
    for (int i=0;i<4;i++){
        int r = r0 + ty*4 + i;
        #pragma unroll
        for (int j=0;j<4;j++){
            int o = o0 + tx*4 + j;
            float v = acc[i][j];
            if (bias) v += bias[o];
            if (resmode==1) v += res[(size_t)r*O + o];
            else if (resmode==2){
                int b = r >> 10, n = r & 1023;
                v += res[((size_t)(b*CDIM+o))*NT + n];
            }
            out[(size_t)r*O + o] = v;
        }
    }
}

// FF1 fused GEGLU: out[r,j] = (A.W1a^T + b1a) * gelu(A.W1g^T + b1g); j in [0,2048)
__global__ __launch_bounds__(256) void ff1_geglu(
        const float* __restrict__ A, const float* __restrict__ W,
        const float* __restrict__ b1, float* __restrict__ out){
    __shared__ float As[64][17], Ba[64][17], Bg[64][17];
    int r0 = blockIdx.x*64, j0 = blockIdx.y*64;
    int tid=threadIdx.x, tx=tid&15, ty=tid>>4, lr=tid>>2, ls=tid&3;
    float acca[4][4]={}, accg[4][4]={};
    for (int k0=0;k0<512;k0+=16){
        float4 av  = *(const float4*)(A + (size_t)(r0+lr)*512 + k0+ls*4);
        float4 bav = *(const float4*)(W + (size_t)(j0+lr)*512 + k0+ls*4);
        float4 bgv = *(const float4*)(W + (size_t)(2048+j0+lr)*512 + k0+ls*4);
        As[lr][ls*4+0]=av.x;  As[lr][ls*4+1]=av.y;  As[lr][ls*4+2]=av.z;  As[lr][ls*4+3]=av.w;
        Ba[lr][ls*4+0]=bav.x; Ba[lr][ls*4+1]=bav.y; Ba[lr][ls*4+2]=bav.z; Ba[lr][ls*4+3]=bav.w;
        Bg[lr][ls*4+0]=bgv.x; Bg[lr][ls*4+1]=bgv.y; Bg[lr][ls*4+2]=bgv.z; Bg[lr][ls*4+3]=bgv.w;
        __syncthreads();
        #pragma unroll
        for (int kk=0;kk<16;kk++){
            float a[4], ba[4], bg[4];
            #pragma unroll
            for (int i=0;i<4;i++) a[i]  = As[ty*4+i][kk];
            #pragma unroll
            for (int j=0;j<4;j++){ ba[j] = Ba[tx*4+j][kk]; bg[j] = Bg[tx*4+j][kk]; }
            #pragma unroll
            for (int i=0;i<4;i++)
                #pragma unroll
                for (int j=0;j<4;j++){ acca[i][j] += a[i]*ba[j]; accg[i][j] += a[i]*bg[j]; }
        }
        __syncthreads();
    }
    #pragma unroll
    for (int i=0;i<4;i++){
        int r = r0 + ty*4 + i;
        #pragma unroll
        for (int j=0;j<4;j++){
            int jj = j0 + tx*4 + j;
            float a = acca[i][j] + b1[jj];
            float g = accg[i][j] + b1[2048+jj];
            float gl = 0.5f*g*(1.0f + erff(g*0.70710678118654752f));
            out[(size_t)r*DFFI + jj] = a*gl;
        }
    }
}

// attention: one block per (b,h,query-row). scores kept in LDS; two-pass softmax
__global__ __launch_bounds__(256) void attn(
        const float* __restrict__ q, const float* __restrict__ k,
        const float* __restrict__ v, float* __restrict__ o,
        int Nq, int Nk, float scale){
    int idx = blockIdx.x;
    int i = idx % Nq;
    int h = (idx / Nq) & 7;
    int b = idx / (Nq*8);
    int tid = threadIdx.x;
    __shared__ float qs[64];
    __shared__ float sc[1024];
    __shared__ float red[256];
    const float* qr = q + ((size_t)(b*Nq + i)*512 + h*64);
    if (tid < 64) qs[tid] = qr[tid];
    __syncthreads();
    float lmax = -1e30f;
    for (int j = tid; j < Nk; j += 256){
        const float* kr = k + ((size_t)(b*Nk + j)*512 + h*64);
        float dot = 0.f;
        #pragma unroll
        for (int d4=0; d4<16; d4++){
            float4 kv = ((const float4*)kr)[d4];
            dot += qs[d4*4+0]*kv.x + qs[d4*4+1]*kv.y + qs[d4*4+2]*kv.z + qs[d4*4+3]*kv.w;
        }
        float s = dot*scale;
        sc[j] = s;
        lmax = fmaxf(lmax, s);
    }
    red[tid]=lmax; __syncthreads();
    for (int st=128; st>0; st>>=1){ if (tid<st) red[tid]=fmaxf(red[tid],red[tid+st]); __syncthreads(); }
    float M = red[0]; __syncthreads();
    float lsum=0.f;
    for (int j=tid; j<Nk; j+=256){ float p = __expf(sc[j]-M); sc[j]=p; lsum+=p; }
    red[tid]=lsum; __syncthreads();
    for (int st=128; st>0; st>>=1){ if (tid<st) red[tid]+=red[tid+st]; __syncthreads(); }
    float L = red[0]; __syncthreads();
    int d = tid & 63, g = tid >> 6;
    int chunk = Nk >> 2;
    float acc = 0.f;
    const float* vb = v + (size_t)(b*Nk)*512 + h*64 + d;
    for (int j = g*chunk; j < (g+1)*chunk; ++j) acc += sc[j]*vb[(size_t)j*512];
    red[tid]=acc; __syncthreads();
    if (tid < 64){
        o[((size_t)(b*Nq+i)*512 + h*64) + d] = (red[d]+red[64+d]+red[128+d]+red[192+d]) / L;
    }
}

// context [B,512,256] -> ctx_t [B*256, 512]
__global__ void transpose_ctx(const float* __restrict__ in, float* __restrict__ out){
    __shared__ float tile[32][33];
    int m0 = blockIdx.x*32, c0 = blockIdx.y*32, b = blockIdx.z;
    int tx=threadIdx.x, ty=threadIdx.y;
    #pragma unroll
    for (int k=0;k<4;k++){
        int c = c0+ty+k*8;
        tile[ty+k*8][tx] = in[((size_t)(b*512+c))*MT + m0+tx];
    }
    __syncthreads();
    #pragma unroll
    for (int k=0;k<4;k++){
        int m = m0+ty+k*8, c = c0+tx;
        out[((size_t)(b*MT+m))*512 + c] = tile[tx][ty+k*8];
    }
}

// token-major [B*1024,512] -> out [B,512,1024]
__global__ void transpose_out(const float* __restrict__ in, float* __restrict__ out){
    __shared__ float tile[32][33];
    int n0 = blockIdx.x*32, c0 = blockIdx.y*32, b=blockIdx.z;
    int tx=threadIdx.x, ty=threadIdx.y;
    #pragma unroll
    for (int k=0;k<4;k++){
        int n = n0+ty+k*8;
        tile[ty+k*8][tx] = in[((size_t)(b*NT+n))*512 + c0+tx];
    }
    __syncthreads();
    #pragma unroll
    for (int k=0;k<4;k++){
        int c = c0+ty+k*8, n = n0+tx;
        out[((size_t)(b*512+c))*NT + n] = tile[tx][ty+k*8];
    }
}

extern "C" void kernel_launch(void* const* d_in, const int* in_sizes, int n_in,
                              void* d_out, int out_size, void* d_ws, size_t ws_size,
                              hipStream_t stream) {
    const float* x      = (const float*)d_in[0];
    const float* emb    = (const float*)d_in[1];
    const float* context= (const float*)d_in[2];
    const float* w_emb  = (const float*)d_in[3];
    const float* b_emb  = (const float*)d_in[4];
    const float* gn_g   = (const float*)d_in[5];
    const float* gn_b   = (const float*)d_in[6];
    const float* conv_w = (const float*)d_in[7];
    const float* conv_b = (const float*)d_in[8];
    const float* a1_wq  = (const float*)d_in[9];
    const float* a1_wk  = (const float*)d_in[10];
    const float* a1_wv  = (const float*)d_in[11];
    const float* a1_wo  = (const float*)d_in[12];
    const float* a1_bo  = (const float*)d_in[13];
    const float* a2_wq  = (const float*)d_in[14];
    const float* a2_wk  = (const float*)d_in[15];
    const float* a2_wv  = (const float*)d_in[16];
    const float* a2_wo  = (const float*)d_in[17];
    const float* a2_bo  = (const float*)d_in[18];
    const float* ln1_g  = (const float*)d_in[19];
    const float* ln1_b  = (const float*)d_in[20];
    const float* ln2_g  = (const float*)d_in[21];
    const float* ln2_b  = (const float*)d_in[22];
    const float* ln3_g  = (const float*)d_in[23];
    const float* ln3_b  = (const float*)d_in[24];
    const float* ff_w1  = (const float*)d_in[25];
    const float* ff_b1  = (const float*)d_in[26];
    const float* ff_w2  = (const float*)d_in[27];
    const float* ff_b2  = (const float*)d_in[28];
    float* out = (float*)d_out;

    float* ws   = (float*)d_ws;
    float* SS   = ws;                         // 8192
    float* STATS= ws + 8192;                  // 512
    float* CTX  = ws + 8704;                  // 2048*512 = 1048576
    const size_t WSZ = (size_t)8192*512;      // 4194304
    float* W0 = CTX + (size_t)2048*512;
    float* W1 = W0 + WSZ;
    float* W2 = W1 + WSZ;
    float* W3 = W2 + WSZ;
    float* W4 = W3 + WSZ;
    float* W5 = W4 + WSZ;
    float* ACT2 = W3;   // aliases W3..W5 + 4M beyond W5 (dead by FF time)

    dim3 tb(32,8);

    // residual conv branch
    emb_gemm<<<32,256,0,stream>>>(emb, w_emb, b_emb, SS);
    gn_stats<<<256,256,0,stream>>>(x, STATS);
    mod_act<<<dim3(32,16,8), tb, 0, stream>>>(x, STATS, gn_g, gn_b, SS, W0);
    gemm_tn<<<dim3(128,8),256,0,stream>>>(W0, conv_w, conv_b, x, W1, 512, 512, 2);   // xt0 = W1
    transpose_ctx<<<dim3(8,16,8), tb, 0, stream>>>(context, CTX);

    // self attention
    ln_rows<<<8192,256,0,stream>>>(W1, ln1_g, ln1_b, W2);
    gemm_tn<<<dim3(128,8),256,0,stream>>>(W2, a1_wq, nullptr, nullptr, W3, 512, 512, 0);
    gemm_tn<<<dim3(128,8),256,0,stream>>>(W2, a1_wk, nullptr, nullptr, W4, 512, 512, 0);
    gemm_tn<<<dim3(128,8),256,0,stream>>>(W2, a1_wv, nullptr, nullptr, W5, 512, 512, 0);
    attn<<<65536,256,0,stream>>>(W3, W4, W5, W0, 1024, 1024, 0.125f);
    gemm_tn<<<dim3(128,8),256,0,stream>>>(W0, a1_wo, a1_bo, W1, W2, 512, 512, 1);    // xt1 = W2

    // cross attention
    ln_rows<<<8192,256,0,stream>>>(W2, ln2_g, ln2_b, W1);                            // y2 = W1
    gemm_tn<<<dim3(128,8),256,0,stream>>>(W1, a2_wq, nullptr, nullptr, W3, 512, 512, 0);
    gemm_tn<<<dim3(32,8),256,0,stream>>>(CTX, a2_wk, nullptr, nullptr, W4, 512, 512, 0);
    gemm_tn<<<dim3(32,8),256,0,stream>>>(CTX, a2_wv, nullptr, nullptr, W5, 512, 512, 0);
    attn<<<65536,256,0,stream>>>(W3, W4, W5, W0, 1024, 256, 0.125f);
    gemm_tn<<<dim3(128,8),256,0,stream>>>(W0, a2_wo, a2_bo, W2, W1, 512, 512, 1);    // xt2 = W1

    // GEGLU FF
    ln_rows<<<8192,256,0,stream>>>(W1, ln3_g, ln3_b, W2);                            // y3 = W2
    ff1_geglu<<<dim3(128,32),256,0,stream>>>(W2, ff_w1, ff_b1, ACT2);
    gemm_tn<<<dim3(128,8),256,0,stream>>>(ACT2, ff_w2, ff_b2, W1, W0, 2048, 512, 1);
    transpose_out<<<dim3(32,16,8), tb, 0, stream>>>(W0, out);
}

// Round 2
// 740.774 us; speedup vs baseline: 9.7124x; 9.7124x over previous
//
#include <hip/hip_runtime.h>
#include <math.h>

#define NB 8
#define CDIM 512
#define NT 1024
#define MT 256
#define DFFI 2048   // GEGLU inner half

typedef short bf16x8 __attribute__((ext_vector_type(8)));
typedef float f32x4 __attribute__((ext_vector_type(4)));

__device__ __forceinline__ float sigmoidf_(float v){ return 1.0f/(1.0f+__expf(-v)); }

__device__ __forceinline__ short f2bf(float f){
    union { float f; unsigned u; } v; v.f = f;
    unsigned r = v.u + 0x7FFFu + ((v.u >> 16) & 1u);
    return (short)(r >> 16);
}

// ---------------- small elementwise / norm kernels (f32) ----------------

__global__ void emb_gemm(const float* __restrict__ emb, const float* __restrict__ w,
                         const float* __restrict__ bias, float* __restrict__ out){
    int idx = blockIdx.x*256 + threadIdx.x;   // 8*1024 total
    int b = idx >> 10, o = idx & 1023;
    const float* e = emb + b*128;
    const float* wr = w + (size_t)o*128;
    float acc = 0.f;
    for (int i=0;i<128;i++){ float ev=e[i]; acc += (ev*sigmoidf_(ev))*wr[i]; }
    out[idx] = acc + bias[o];
}

__global__ void gn_stats(const float* __restrict__ x, float* __restrict__ stats){
    int bg = blockIdx.x;               // b*32+g
    const float* base = x + (size_t)bg*16*NT;
    float s=0.f, sq=0.f;
    for (int i=threadIdx.x; i<16*NT; i+=256){ float v = base[i]; s+=v; sq+=v*v; }
    __shared__ float rs[256], rq[256];
    rs[threadIdx.x]=s; rq[threadIdx.x]=sq; __syncthreads();
    for (int st=128; st>0; st>>=1){
        if (threadIdx.x<st){ rs[threadIdx.x]+=rs[threadIdx.x+st]; rq[threadIdx.x]+=rq[threadIdx.x+st]; }
        __syncthreads();
    }
    if (threadIdx.x==0){
        float mu = rs[0]/(16.f*NT);
        float var = rq[0]/(16.f*NT) - mu*mu;
        stats[2*bg] = mu; stats[2*bg+1] = rsqrtf(var + 1e-6f);
    }
}

__global__ void mod_act(const float* __restrict__ x, const float* __restrict__ stats,
                        const float* __restrict__ gg, const float* __restrict__ gb,
                        const float* __restrict__ ss, float* __restrict__ act_t){
    __shared__ float tile[32][33];
    int n0 = blockIdx.x*32, c0 = blockIdx.y*32, b = blockIdx.z;
    int tx = threadIdx.x, ty = threadIdx.y;
    #pragma unroll
    for (int k=0;k<4;k++){
        int c = c0 + ty + k*8;
        tile[ty+k*8][tx] = x[((size_t)(b*CDIM+c))*NT + n0 + tx];
    }
    __syncthreads();
    #pragma unroll
    for (int k=0;k<4;k++){
        int c = c0 + tx, n = n0 + ty + k*8;
        float raw = tile[tx][ty+k*8];
        int gi = b*32 + (c>>4);
        float v = (raw - stats[2*gi]) * stats[2*gi+1] * gg[c] + gb[c];
        v = v * (1.f + ss[b*1024 + c]) + ss[b*1024 + 512 + c];
        act_t[((size_t)(b*NT+n))*CDIM + c] = v * sigmoidf_(v);
    }
}

__global__ void ln_rows(const float* __restrict__ in, const float* __restrict__ g,
                        const float* __restrict__ bta, float* __restrict__ out){
    int row = blockIdx.x;
    const float* base = in + (size_t)row*CDIM;
    int t = threadIdx.x;
    float v0 = base[t], v1 = base[t+256];
    __shared__ float rs[256], rq[256];
    rs[t]=v0+v1; rq[t]=v0*v0+v1*v1; __syncthreads();
    for (int st=128; st>0; st>>=1){
        if (t<st){ rs[t]+=rs[t+st]; rq[t]+=rq[t+st]; }
        __syncthreads();
    }
    float mu = rs[0]*(1.f/512.f);
    float var = rq[0]*(1.f/512.f) - mu*mu;
    float rstd = rsqrtf(var + 1e-5f);
    out[(size_t)row*CDIM + t]     = (v0-mu)*rstd*g[t]+bta[t];
    out[(size_t)row*CDIM + t+256] = (v1-mu)*rstd*g[t+256]+bta[t+256];
}

// ---------------- bf16 MFMA GEMM: out[r,o] = A[r,:].W[o,:] (+bias)(+res) ----------------
// A: [rows,K] f32, W: [O,K] f32. 64x64 tile/block, 4 waves, BK=32.
// resmode: 0 none, 1 res[r*O+o], 2 res[(b*512+o)*1024+n] with r=b*1024+n
__global__ __launch_bounds__(256) void gemm_bf16(
        const float* __restrict__ A, const float* __restrict__ W,
        const float* __restrict__ bias, const float* __restrict__ res,
        float* __restrict__ out, int K, int O, int resmode){
    __shared__ short As[64][40], Bs[64][40];   // +8 pad, rows 80B (16B-aligned)
    int r0 = blockIdx.x*64, o0 = blockIdx.y*64;
    int tid = threadIdx.x;
    int w = tid >> 6, lane = tid & 63;
    int quad = lane >> 4, lw = lane & 15;
    int srow = tid >> 2, sseg = tid & 3;       // staging: row 0..63, 8 k each
    f32x4 acc[4] = {};
    for (int k0 = 0; k0 < K; k0 += 32){
        const float* ap = A + (size_t)(r0+srow)*K + k0 + sseg*8;
        const float* bp = W + (size_t)(o0+srow)*K + k0 + sseg*8;
        float4 a0 = ((const float4*)ap)[0], a1 = ((const float4*)ap)[1];
        float4 b0 = ((const float4*)bp)[0], b1 = ((const float4*)bp)[1];
        bf16x8 av, bv;
        av[0]=f2bf(a0.x); av[1]=f2bf(a0.y); av[2]=f2bf(a0.z); av[3]=f2bf(a0.w);
        av[4]=f2bf(a1.x); av[5]=f2bf(a1.y); av[6]=f2bf(a1.z); av[7]=f2bf(a1.w);
        bv[0]=f2bf(b0.x); bv[1]=f2bf(b0.y); bv[2]=f2bf(b0.z); bv[3]=f2bf(b0.w);
        bv[4]=f2bf(b1.x); bv[5]=f2bf(b1.y); bv[6]=f2bf(b1.z); bv[7]=f2bf(b1.w);
        *(bf16x8*)&As[srow][sseg*8] = av;
        *(bf16x8*)&Bs[srow][sseg*8] = bv;
        __syncthreads();
        bf16x8 af = *(const bf16x8*)&As[w*16 + lw][quad*8];
        #pragma unroll
        for (int ct=0; ct<4; ct++){
            bf16x8 bf = *(const bf16x8*)&Bs[ct*16 + lw][quad*8];
            acc[ct] = __builtin_amdgcn_mfma_f32_16x16x32_bf16(af, bf, acc[ct], 0, 0, 0);
        }
        __syncthreads();
    }
    #pragma unroll
    for (int ct=0; ct<4; ct++){
        #pragma unroll
        for (int reg=0; reg<4; reg++){
            int r = r0 + w*16 + quad*4 + reg;
            int o = o0 + ct*16 + lw;
            float v = acc[ct][reg];
            if (bias) v += bias[o];
            if (resmode==1) v += res[(size_t)r*O + o];
            else if (resmode==2){
                int b = r >> 10, n = r & 1023;
                v += res[((size_t)(b*CDIM+o))*NT + n];
            }
            out[(size_t)r*O + o] = v;
        }
    }
}

// ---------------- FF1 fused GEGLU (bf16 MFMA) ----------------
// out[r,j] = (A.W1a^T + b1a[j]) * gelu(A.W1g^T + b1g[j]); j in [0,2048), K=512
__global__ __launch_bounds__(256) void ff1_geglu_bf16(
        const float* __restrict__ A, const float* __restrict__ W,
        const float* __restrict__ b1, float* __restrict__ out){
    __shared__ short As[64][40], Ba[64][40], Bg[64][40];
    int r0 = blockIdx.x*64, j0 = blockIdx.y*64;
    int tid = threadIdx.x;
    int w = tid >> 6, lane = tid & 63;
    int quad = lane >> 4, lw = lane & 15;
    int srow = tid >> 2, sseg = tid & 3;
    f32x4 acca[4] = {}, accg[4] = {};
    for (int k0 = 0; k0 < 512; k0 += 32){
        const float* ap  = A + (size_t)(r0+srow)*512 + k0 + sseg*8;
        const float* bap = W + (size_t)(j0+srow)*512 + k0 + sseg*8;
        const float* bgp = W + (size_t)(2048+j0+srow)*512 + k0 + sseg*8;
        float4 a0=((const float4*)ap)[0],  a1=((const float4*)ap)[1];
        float4 c0=((const float4*)bap)[0], c1=((const float4*)bap)[1];
        float4 g0=((const float4*)bgp)[0], g1=((const float4*)bgp)[1];
        bf16x8 av, cv, gv;
        av[0]=f2bf(a0.x); av[1]=f2bf(a0.y); av[2]=f2bf(a0.z); av[3]=f2bf(a0.w);
        av[4]=f2bf(a1.x); av[5]=f2bf(a1.y); av[6]=f2bf(a1.z); av[7]=f2bf(a1.w);
        cv[0]=f2bf(c0.x); cv[1]=f2bf(c0.y); cv[2]=f2bf(c0.z); cv[3]=f2bf(c0.w);
        cv[4]=f2bf(c1.x); cv[5]=f2bf(c1.y); cv[6]=f2bf(c1.z); cv[7]=f2bf(c1.w);
        gv[0]=f2bf(g0.x); gv[1]=f2bf(g0.y); gv[2]=f2bf(g0.z); gv[3]=f2bf(g0.w);
        gv[4]=f2bf(g1.x); gv[5]=f2bf(g1.y); gv[6]=f2bf(g1.z); gv[7]=f2bf(g1.w);
        *(bf16x8*)&As[srow][sseg*8] = av;
        *(bf16x8*)&Ba[srow][sseg*8] = cv;
        *(bf16x8*)&Bg[srow][sseg*8] = gv;
        __syncthreads();
        bf16x8 af = *(const bf16x8*)&As[w*16 + lw][quad*8];
        #pragma unroll
        for (int ct=0; ct<4; ct++){
            bf16x8 ba = *(const bf16x8*)&Ba[ct*16 + lw][quad*8];
            bf16x8 bg = *(const bf16x8*)&Bg[ct*16 + lw][quad*8];
            acca[ct] = __builtin_amdgcn_mfma_f32_16x16x32_bf16(af, ba, acca[ct], 0, 0, 0);
            accg[ct] = __builtin_amdgcn_mfma_f32_16x16x32_bf16(af, bg, accg[ct], 0, 0, 0);
        }
        __syncthreads();
    }
    #pragma unroll
    for (int ct=0; ct<4; ct++){
        #pragma unroll
        for (int reg=0; reg<4; reg++){
            int r = r0 + w*16 + quad*4 + reg;
            int jj = j0 + ct*16 + lw;
            float a = acca[ct][reg] + b1[jj];
            float g = accg[ct][reg] + b1[2048+jj];
            float gl = 0.5f*g*(1.0f + erff(g*0.70710678118654752f));
            out[(size_t)r*DFFI + jj] = a*gl;
        }
    }
}

// ---------------- flash-style bf16 MFMA attention ----------------
// one block = (b, h, 64-query tile); 4 waves x 16 query rows; loop over 64-key tiles
__global__ __launch_bounds__(256) void attn_mfma(
        const float* __restrict__ q, const float* __restrict__ k,
        const float* __restrict__ v, float* __restrict__ o,
        int Nq, int Nk, float scale){
    __shared__ short Qs[64][72];
    __shared__ short Ks[64][72];
    __shared__ short Vt[64][72];   // [d][key]
    __shared__ short Ps[64][72];   // 4 waves x 16 rows, cols = keys
    int qt = blockIdx.x & ((Nq>>6)-1);
    int h  = (blockIdx.x / (Nq>>6)) & 7;
    int b  = blockIdx.x / ((Nq>>6)*8);
    int tid = threadIdx.x;
    int w = tid >> 6, lane = tid & 63;
    int quad = lane >> 4, lw = lane & 15;
    int srow = tid >> 2, sseg = tid & 3;     // staging: row 0..63, 16 d each
    int q0 = qt*64;

    // stage Q (scale folded in)
    {
        const float* qp = q + ((size_t)(b*Nq + q0 + srow)*512 + h*64 + sseg*16);
        float4 x0=((const float4*)qp)[0], x1=((const float4*)qp)[1],
               x2=((const float4*)qp)[2], x3=((const float4*)qp)[3];
        bf16x8 v0, v1;
        v0[0]=f2bf(x0.x*scale); v0[1]=f2bf(x0.y*scale); v0[2]=f2bf(x0.z*scale); v0[3]=f2bf(x0.w*scale);
        v0[4]=f2bf(x1.x*scale); v0[5]=f2bf(x1.y*scale); v0[6]=f2bf(x1.z*scale); v0[7]=f2bf(x1.w*scale);
        v1[0]=f2bf(x2.x*scale); v1[1]=f2bf(x2.y*scale); v1[2]=f2bf(x2.z*scale); v1[3]=f2bf(x2.w*scale);
        v1[4]=f2bf(x3.x*scale); v1[5]=f2bf(x3.y*scale); v1[6]=f2bf(x3.z*scale); v1[7]=f2bf(x3.w*scale);
        *(bf16x8*)&Qs[srow][sseg*16]   = v0;
        *(bf16x8*)&Qs[srow][sseg*16+8] = v1;
    }
    __syncthreads();
    bf16x8 qf0 = *(const bf16x8*)&Qs[w*16 + lw][quad*8];
    bf16x8 qf1 = *(const bf16x8*)&Qs[w*16 + lw][32 + quad*8];

    f32x4 oacc[4] = {};
    float m_[4] = {-1e30f,-1e30f,-1e30f,-1e30f};
    float l_[4] = {0.f,0.f,0.f,0.f};

    int nkt = Nk >> 6;
    for (int kt = 0; kt < nkt; kt++){
        __syncthreads();
        // stage K tile + V tile (transposed)
        {
            const float* kp = k + ((size_t)(b*Nk + kt*64 + srow)*512 + h*64 + sseg*16);
            float4 x0=((const float4*)kp)[0], x1=((const float4*)kp)[1],
                   x2=((const float4*)kp)[2], x3=((const float4*)kp)[3];
            bf16x8 v0, v1;
            v0[0]=f2bf(x0.x); v0[1]=f2bf(x0.y); v0[2]=f2bf(x0.z); v0[3]=f2bf(x0.w);
            v0[4]=f2bf(x1.x); v0[5]=f2bf(x1.y); v0[6]=f2bf(x1.z); v0[7]=f2bf(x1.w);
            v1[0]=f2bf(x2.x); v1[1]=f2bf(x2.y); v1[2]=f2bf(x2.z); v1[3]=f2bf(x2.w);
            v1[4]=f2bf(x3.x); v1[5]=f2bf(x3.y); v1[6]=f2bf(x3.z); v1[7]=f2bf(x3.w);
            *(bf16x8*)&Ks[srow][sseg*16]   = v0;
            *(bf16x8*)&Ks[srow][sseg*16+8] = v1;
            const float* vp = v + ((size_t)(b*Nk + kt*64 + srow)*512 + h*64 + sseg*16);
            float4 y0=((const float4*)vp)[0], y1=((const float4*)vp)[1],
                   y2=((const float4*)vp)[2], y3=((const float4*)vp)[3];
            float vals[16] = {y0.x,y0.y,y0.z,y0.w, y1.x,y1.y,y1.z,y1.w,
                              y2.x,y2.y,y2.z,y2.w, y3.x,y3.y,y3.z,y3.w};
            #pragma unroll
            for (int i=0;i<16;i++) Vt[sseg*16+i][srow] = f2bf(vals[i]);
        }
        __syncthreads();

        // S = Q.K^T (scaled)
        f32x4 s[4] = {};
        #pragma unroll
        for (int ct=0; ct<4; ct++){
            bf16x8 kf0 = *(const bf16x8*)&Ks[ct*16 + lw][quad*8];
            bf16x8 kf1 = *(const bf16x8*)&Ks[ct*16 + lw][32 + quad*8];
            s[ct] = __builtin_amdgcn_mfma_f32_16x16x32_bf16(qf0, kf0, s[ct], 0, 0, 0);
            s[ct] = __builtin_amdgcn_mfma_f32_16x16x32_bf16(qf1, kf1, s[ct], 0, 0, 0);
        }

        // online softmax over this key tile (rows = quad*4+reg)
        float mx[4], sm[4], alpha[4];
        #pragma unroll
        for (int r=0;r<4;r++){
            float mv = fmaxf(fmaxf(s[0][r], s[1][r]), fmaxf(s[2][r], s[3][r]));
            #pragma unroll
            for (int off=8; off>0; off>>=1) mv = fmaxf(mv, __shfl_xor(mv, off, 16));
            float mn = fmaxf(m_[r], mv);
            alpha[r] = __expf(m_[r] - mn);
            m_[r] = mn;
            mx[r] = mn;
        }
        float p[4][4];
        #pragma unroll
        for (int ct=0; ct<4; ct++)
            #pragma unroll
            for (int r=0;r<4;r++) p[ct][r] = __expf(s[ct][r] - mx[r]);
        #pragma unroll
        for (int r=0;r<4;r++){
            float sv = p[0][r]+p[1][r]+p[2][r]+p[3][r];
            #pragma unroll
            for (int off=8; off>0; off>>=1) sv += __shfl_xor(sv, off, 16);
            sm[r] = sv;
            l_[r] = l_[r]*alpha[r] + sv;
        }
        // write P to LDS (C-layout -> row-major)
        #pragma unroll
        for (int ct=0; ct<4; ct++)
            #pragma unroll
            for (int r=0;r<4;r++)
                Ps[w*16 + quad*4 + r][ct*16 + lw] = f2bf(p[ct][r]);
        __asm__ volatile("s_waitcnt lgkmcnt(0)" ::: "memory");

        // O = O*alpha + P.V
        #pragma unroll
        for (int dt=0; dt<4; dt++)
            #pragma unroll
            for (int r=0;r<4;r++) oacc[dt][r] *= alpha[r];
        bf16x8 pf0 = *(const bf16x8*)&Ps[w*16 + lw][quad*8];
        bf16x8 pf1 = *(const bf16x8*)&Ps[w*16 + lw][32 + quad*8];
        #pragma unroll
        for (int dt=0; dt<4; dt++){
            bf16x8 vf0 = *(const bf16x8*)&Vt[dt*16 + lw][quad*8];
            bf16x8 vf1 = *(const bf16x8*)&Vt[dt*16 + lw][32 + quad*8];
            oacc[dt] = __builtin_amdgcn_mfma_f32_16x16x32_bf16(pf0, vf0, oacc[dt], 0, 0, 0);
            oacc[dt] = __builtin_amdgcn_mfma_f32_16x16x32_bf16(pf1, vf1, oacc[dt], 0, 0, 0);
        }
        (void)sm;
    }
    // epilogue: divide by l, store
    #pragma unroll
    for (int dt=0; dt<4; dt++){
        #pragma unroll
        for (int r=0;r<4;r++){
            int qi = q0 + w*16 + quad*4 + r;
            o[((size_t)(b*Nq + qi)*512 + h*64 + dt*16 + lw)] = oacc[dt][r] / l_[r];
        }
    }
}

// ---------------- layout transposes ----------------

__global__ void transpose_ctx(const float* __restrict__ in, float* __restrict__ out){
    __shared__ float tile[32][33];
    int m0 = blockIdx.x*32, c0 = blockIdx.y*32, b = blockIdx.z;
    int tx=threadIdx.x, ty=threadIdx.y;
    #pragma unroll
    for (int k=0;k<4;k++){
        int c = c0+ty+k*8;
        tile[ty+k*8][tx] = in[((size_t)(b*512+c))*MT + m0+tx];
    }
    __syncthreads();
    #pragma unroll
    for (int k=0;k<4;k++){
        int m = m0+ty+k*8, c = c0+tx;
        out[((size_t)(b*MT+m))*512 + c] = tile[tx][ty+k*8];
    }
}

__global__ void transpose_out(const float* __restrict__ in, float* __restrict__ out){
    __shared__ float tile[32][33];
    int n0 = blockIdx.x*32, c0 = blockIdx.y*32, b=blockIdx.z;
    int tx=threadIdx.x, ty=threadIdx.y;
    #pragma unroll
    for (int k=0;k<4;k++){
        int n = n0+ty+k*8;
        tile[ty+k*8][tx] = in[((size_t)(b*NT+n))*512 + c0+tx];
    }
    __syncthreads();
    #pragma unroll
    for (int k=0;k<4;k++){
        int c = c0+ty+k*8, n = n0+tx;
        out[((size_t)(b*512+c))*NT + n] = tile[tx][ty+k*8];
    }
}

extern "C" void kernel_launch(void* const* d_in, const int* in_sizes, int n_in,
                              void* d_out, int out_size, void* d_ws, size_t ws_size,
                              hipStream_t stream) {
    const float* x      = (const float*)d_in[0];
    const float* emb    = (const float*)d_in[1];
    const float* context= (const float*)d_in[2];
    const float* w_emb  = (const float*)d_in[3];
    const float* b_emb  = (const float*)d_in[4];
    const float* gn_g   = (const float*)d_in[5];
    const float* gn_b   = (const float*)d_in[6];
    const float* conv_w = (const float*)d_in[7];
    const float* conv_b = (const float*)d_in[8];
    const float* a1_wq  = (const float*)d_in[9];
    const float* a1_wk  = (const float*)d_in[10];
    const float* a1_wv  = (const float*)d_in[11];
    const float* a1_wo  = (const float*)d_in[12];
    const float* a1_bo  = (const float*)d_in[13];
    const float* a2_wq  = (const float*)d_in[14];
    const float* a2_wk  = (const float*)d_in[15];
    const float* a2_wv  = (const float*)d_in[16];
    const float* a2_wo  = (const float*)d_in[17];
    const float* a2_bo  = (const float*)d_in[18];
    const float* ln1_g  = (const float*)d_in[19];
    const float* ln1_b  = (const float*)d_in[20];
    const float* ln2_g  = (const float*)d_in[21];
    const float* ln2_b  = (const float*)d_in[22];
    const float* ln3_g  = (const float*)d_in[23];
    const float* ln3_b  = (const float*)d_in[24];
    const float* ff_w1  = (const float*)d_in[25];
    const float* ff_b1  = (const float*)d_in[26];
    const float* ff_w2  = (const float*)d_in[27];
    const float* ff_b2  = (const float*)d_in[28];
    float* out = (float*)d_out;

    float* ws   = (float*)d_ws;
    float* SS   = ws;                         // 8192
    float* STATS= ws + 8192;                  // 512
    float* CTX  = ws + 8704;                  // 2048*512
    const size_t WSZ = (size_t)8192*512;
    float* W0 = CTX + (size_t)2048*512;
    float* W1 = W0 + WSZ;
    float* W2 = W1 + WSZ;
    float* W3 = W2 + WSZ;
    float* W4 = W3 + WSZ;
    float* W5 = W4 + WSZ;
    float* ACT2 = W3;   // [8192,2048] f32, aliases W3..beyond (dead by FF time)

    dim3 tb(32,8);

    // residual conv branch
    emb_gemm<<<32,256,0,stream>>>(emb, w_emb, b_emb, SS);
    gn_stats<<<256,256,0,stream>>>(x, STATS);
    mod_act<<<dim3(32,16,8), tb, 0, stream>>>(x, STATS, gn_g, gn_b, SS, W0);
    gemm_bf16<<<dim3(128,8),256,0,stream>>>(W0, conv_w, conv_b, x, W1, 512, 512, 2);   // xt0 = W1
    transpose_ctx<<<dim3(8,16,8), tb, 0, stream>>>(context, CTX);

    // self attention
    ln_rows<<<8192,256,0,stream>>>(W1, ln1_g, ln1_b, W2);
    gemm_bf16<<<dim3(128,8),256,0,stream>>>(W2, a1_wq, nullptr, nullptr, W3, 512, 512, 0);
    gemm_bf16<<<dim3(128,8),256,0,stream>>>(W2, a1_wk, nullptr, nullptr, W4, 512, 512, 0);
    gemm_bf16<<<dim3(128,8),256,0,stream>>>(W2, a1_wv, nullptr, nullptr, W5, 512, 512, 0);
    attn_mfma<<<1024,256,0,stream>>>(W3, W4, W5, W0, 1024, 1024, 0.125f);
    gemm_bf16<<<dim3(128,8),256,0,stream>>>(W0, a1_wo, a1_bo, W1, W2, 512, 512, 1);    // xt1 = W2

    // cross attention
    ln_rows<<<8192,256,0,stream>>>(W2, ln2_g, ln2_b, W1);                              // y2 = W1
    gemm_bf16<<<dim3(128,8),256,0,stream>>>(W1, a2_wq, nullptr, nullptr, W3, 512, 512, 0);
    gemm_bf16<<<dim3(32,8),256,0,stream>>>(CTX, a2_wk, nullptr, nullptr, W4, 512, 512, 0);
    gemm_bf16<<<dim3(32,8),256,0,stream>>>(CTX, a2_wv, nullptr, nullptr, W5, 512, 512, 0);
    attn_mfma<<<1024,256,0,stream>>>(W3, W4, W5, W0, 1024, 256, 0.125f);
    gemm_bf16<<<dim3(128,8),256,0,stream>>>(W0, a2_wo, a2_bo, W2, W1, 512, 512, 1);    // xt2 = W1

    // GEGLU FF
    ln_rows<<<8192,256,0,stream>>>(W1, ln3_g, ln3_b, W2);                              // y3 = W2
    ff1_geglu_bf16<<<dim3(128,32),256,0,stream>>>(W2, ff_w1, ff_b1, ACT2);
    gemm_bf16<<<dim3(128,8),256,0,stream>>>(ACT2, ff_w2, ff_b2, W1, W0, 2048, 512, 1);
    transpose_out<<<dim3(32,16,8), tb, 0, stream>>>(W0, out);
}

// Round 3
// 620.407 us; speedup vs baseline: 11.5968x; 1.1940x over previous
//
#include <hip/hip_runtime.h>
#include <math.h>

#define NB 8
#define CDIM 512
#define NT 1024
#define MT 256
#define DFFI 2048   // GEGLU inner half

typedef short bf16x8 __attribute__((ext_vector_type(8)));
typedef float f32x4 __attribute__((ext_vector_type(4)));

__device__ __forceinline__ float sigmoidf_(float v){ return 1.0f/(1.0f+__expf(-v)); }

__device__ __forceinline__ short f2bf(float f){
    union { float f; unsigned u; } v; v.f = f;
    unsigned r = v.u + 0x7FFFu + ((v.u >> 16) & 1u);
    return (short)(r >> 16);
}

#define GLDS(gp, lp) __builtin_amdgcn_global_load_lds( \
    (const __attribute__((address_space(1))) void*)(gp), \
    (__attribute__((address_space(3))) void*)(lp), 16, 0, 0)

// ---------------- f32 -> bf16 convert (weights, once per launch) ----------------
__global__ void cvt(const float* __restrict__ s, short* __restrict__ d, int n){
    int i = (blockIdx.x*256 + threadIdx.x)*8;
    if (i >= n) return;
    float4 a = ((const float4*)(s+i))[0], b = ((const float4*)(s+i))[1];
    bf16x8 v;
    v[0]=f2bf(a.x); v[1]=f2bf(a.y); v[2]=f2bf(a.z); v[3]=f2bf(a.w);
    v[4]=f2bf(b.x); v[5]=f2bf(b.y); v[6]=f2bf(b.z); v[7]=f2bf(b.w);
    *(bf16x8*)(d+i) = v;
}

// ---------------- small elementwise / norm kernels ----------------

__global__ void emb_gemm(const float* __restrict__ emb, const float* __restrict__ w,
                         const float* __restrict__ bias, float* __restrict__ out){
    int idx = blockIdx.x*256 + threadIdx.x;   // 8*1024 total
    int b = idx >> 10, o = idx & 1023;
    const float* e = emb + b*128;
    const float* wr = w + (size_t)o*128;
    float acc = 0.f;
    for (int i=0;i<128;i++){ float ev=e[i]; acc += (ev*sigmoidf_(ev))*wr[i]; }
    out[idx] = acc + bias[o];
}

__global__ void gn_stats(const float* __restrict__ x, float* __restrict__ stats){
    int bg = blockIdx.x;               // b*32+g
    const float* base = x + (size_t)bg*16*NT;
    float s=0.f, sq=0.f;
    for (int i=threadIdx.x; i<16*NT; i+=256){ float v = base[i]; s+=v; sq+=v*v; }
    __shared__ float rs[256], rq[256];
    rs[threadIdx.x]=s; rq[threadIdx.x]=sq; __syncthreads();
    for (int st=128; st>0; st>>=1){
        if (threadIdx.x<st){ rs[threadIdx.x]+=rs[threadIdx.x+st]; rq[threadIdx.x]+=rq[threadIdx.x+st]; }
        __syncthreads();
    }
    if (threadIdx.x==0){
        float mu = rs[0]/(16.f*NT);
        float var = rq[0]/(16.f*NT) - mu*mu;
        stats[2*bg] = mu; stats[2*bg+1] = rsqrtf(var + 1e-6f);
    }
}

// modulated GN + SiLU, transposed to token-major, bf16 out
__global__ void mod_act(const float* __restrict__ x, const float* __restrict__ stats,
                        const float* __restrict__ gg, const float* __restrict__ gb,
                        const float* __restrict__ ss, short* __restrict__ act_t){
    __shared__ float tile[32][33];
    int n0 = blockIdx.x*32, c0 = blockIdx.y*32, b = blockIdx.z;
    int tx = threadIdx.x, ty = threadIdx.y;
    #pragma unroll
    for (int k=0;k<4;k++){
        int c = c0 + ty + k*8;
        tile[ty+k*8][tx] = x[((size_t)(b*CDIM+c))*NT + n0 + tx];
    }
    __syncthreads();
    #pragma unroll
    for (int k=0;k<4;k++){
        int c = c0 + tx, n = n0 + ty + k*8;
        float raw = tile[tx][ty+k*8];
        int gi = b*32 + (c>>4);
        float v = (raw - stats[2*gi]) * stats[2*gi+1] * gg[c] + gb[c];
        v = v * (1.f + ss[b*1024 + c]) + ss[b*1024 + 512 + c];
        act_t[((size_t)(b*NT+n))*CDIM + c] = f2bf(v * sigmoidf_(v));
    }
}

// LayerNorm over rows of 512: f32 in -> bf16 out
__global__ void ln_rows(const float* __restrict__ in, const float* __restrict__ g,
                        const float* __restrict__ bta, short* __restrict__ out){
    int row = blockIdx.x;
    const float* base = in + (size_t)row*CDIM;
    int t = threadIdx.x;
    float v0 = base[t], v1 = base[t+256];
    __shared__ float rs[256], rq[256];
    rs[t]=v0+v1; rq[t]=v0*v0+v1*v1; __syncthreads();
    for (int st=128; st>0; st>>=1){
        if (t<st){ rs[t]+=rs[t+st]; rq[t]+=rq[t+st]; }
        __syncthreads();
    }
    float mu = rs[0]*(1.f/512.f);
    float var = rq[0]*(1.f/512.f) - mu*mu;
    float rstd = rsqrtf(var + 1e-5f);
    out[(size_t)row*CDIM + t]     = f2bf((v0-mu)*rstd*g[t]+bta[t]);
    out[(size_t)row*CDIM + t+256] = f2bf((v1-mu)*rstd*g[t+256]+bta[t+256]);
}

// context [B,512,256] -> bf16 token-major [B*256, 512]
__global__ void transpose_ctx(const float* __restrict__ in, short* __restrict__ out){
    __shared__ float tile[32][33];
    int m0 = blockIdx.x*32, c0 = blockIdx.y*32, b = blockIdx.z;
    int tx=threadIdx.x, ty=threadIdx.y;
    #pragma unroll
    for (int k=0;k<4;k++){
        int c = c0+ty+k*8;
        tile[ty+k*8][tx] = in[((size_t)(b*512+c))*MT + m0+tx];
    }
    __syncthreads();
    #pragma unroll
    for (int k=0;k<4;k++){
        int m = m0+ty+k*8, c = c0+tx;
        out[((size_t)(b*MT+m))*512 + c] = f2bf(tile[tx][ty+k*8]);
    }
}

// token-major f32 [B*1024,512] -> out f32 [B,512,1024]
__global__ void transpose_out(const float* __restrict__ in, float* __restrict__ out){
    __shared__ float tile[32][33];
    int n0 = blockIdx.x*32, c0 = blockIdx.y*32, b=blockIdx.z;
    int tx=threadIdx.x, ty=threadIdx.y;
    #pragma unroll
    for (int k=0;k<4;k++){
        int n = n0+ty+k*8;
        tile[ty+k*8][tx] = in[((size_t)(b*NT+n))*512 + c0+tx];
    }
    __syncthreads();
    #pragma unroll
    for (int k=0;k<4;k++){
        int c = c0+ty+k*8, n = n0+tx;
        out[((size_t)(b*512+c))*NT + n] = tile[tx][ty+k*8];
    }
}

// ---------------- m97-style bf16 GEMM: 128x128 tile, BK=64, global_load_lds ----------------
// A [rows,K] bf16, W [O,K] bf16. out = A.W^T (+bias)(+res)
// resmode: 0 none, 1 res[row*O+col] (f32), 2 res[(b*512+col)*1024+n] f32, row=b*1024+n
// output: outf (f32) if non-null else outb (bf16); stride ostr.
__global__ __launch_bounds__(256) void gemm_bb(
        const short* __restrict__ A, const short* __restrict__ W,
        const float* __restrict__ bias, const float* __restrict__ res,
        float* __restrict__ outf, short* __restrict__ outb,
        int K, int O, int ostr, int resmode){
    __shared__ short As[128*64];   // [row][slot*8], slot = seg ^ (row&7)
    __shared__ short Bs[128*64];
    int r0 = blockIdx.x*128, o0 = blockIdx.y*128;
    int tid = threadIdx.x, w = tid>>6, lane = tid&63;
    int quad = lane>>4, lw = lane&15;
    int g_row = lane>>3, g_s = lane&7;      // staging: 8 rows x 8 slots per instr
    int sseg = g_s ^ g_row;                  // XOR swizzle (row&7 == g_row here)
    int wr = (w&1)*64, wc = (w>>1)*64;
    f32x4 acc[4][4] = {};
    for (int k0 = 0; k0 < K; k0 += 64){
        #pragma unroll
        for (int j=0;j<4;j++){
            int row = w*32 + j*8 + g_row;
            GLDS(A + (size_t)(r0+row)*K + k0 + sseg*8, As + (w*32+j*8)*64);
        }
        #pragma unroll
        for (int j=0;j<4;j++){
            int row = w*32 + j*8 + g_row;
            GLDS(W + (size_t)(o0+row)*K + k0 + sseg*8, Bs + (w*32+j*8)*64);
        }
        __syncthreads();
        bf16x8 af[4][2], bf[4][2];
        #pragma unroll
        for (int ks=0; ks<2; ks++){
            #pragma unroll
            for (int i=0;i<4;i++){
                int row = wr + i*16 + lw;
                af[i][ks] = *(const bf16x8*)&As[row*64 + (((ks*4+quad) ^ (lw&7)))*8];
                int col = wc + i*16 + lw;
                bf[i][ks] = *(const bf16x8*)&Bs[col*64 + (((ks*4+quad) ^ (lw&7)))*8];
            }
        }
        #pragma unroll
        for (int ks=0; ks<2; ks++)
            #pragma unroll
            for (int i=0;i<4;i++)
                #pragma unroll
                for (int j=0;j<4;j++)
                    acc[i][j] = __builtin_amdgcn_mfma_f32_16x16x32_bf16(af[i][ks], bf[j][ks], acc[i][j], 0, 0, 0);
        __syncthreads();
    }
    #pragma unroll
    for (int i=0;i<4;i++){
        #pragma unroll
        for (int j=0;j<4;j++){
            #pragma unroll
            for (int reg=0; reg<4; reg++){
                int row = r0 + wr + i*16 + quad*4 + reg;
                int col = o0 + wc + j*16 + lw;
                float v = acc[i][j][reg];
                if (bias) v += bias[col];
                if (resmode==1) v += res[(size_t)row*O + col];
                else if (resmode==2){
                    int b = row >> 10, n = row & 1023;
                    v += res[((size_t)(b*CDIM+col))*NT + n];
                }
                if (outf) outf[(size_t)row*ostr + col] = v;
                else      outb[(size_t)row*ostr + col] = f2bf(v);
            }
        }
    }
}

// ---------------- FF1 fused GEGLU, 128x64 tile (x2 gates), BK=64 ----------------
__global__ __launch_bounds__(256) void ff1_geglu_bb(
        const short* __restrict__ A, const short* __restrict__ W,
        const float* __restrict__ b1, short* __restrict__ out){
    __shared__ short As[128*64];
    __shared__ short Ba[64*64];
    __shared__ short Bg[64*64];
    int r0 = blockIdx.x*128, j0 = blockIdx.y*64;
    int tid = threadIdx.x, w = tid>>6, lane = tid&63;
    int quad = lane>>4, lw = lane&15;
    int g_row = lane>>3, g_s = lane&7;
    int sseg = g_s ^ g_row;
    int wr = (w&1)*64, wc = (w>>1)*32;
    f32x4 acca[4][2] = {}, accg[4][2] = {};
    for (int k0 = 0; k0 < 512; k0 += 64){
        #pragma unroll
        for (int j=0;j<4;j++){
            int row = w*32 + j*8 + g_row;
            GLDS(A + (size_t)(r0+row)*512 + k0 + sseg*8, As + (w*32+j*8)*64);
        }
        #pragma unroll
        for (int j=0;j<2;j++){
            int row = w*16 + j*8 + g_row;
            GLDS(W + (size_t)(j0+row)*512 + k0 + sseg*8, Ba + (w*16+j*8)*64);
            GLDS(W + (size_t)(2048+j0+row)*512 + k0 + sseg*8, Bg + (w*16+j*8)*64);
        }
        __syncthreads();
        bf16x8 af[4][2], ba[2][2], bg[2][2];
        #pragma unroll
        for (int ks=0; ks<2; ks++){
            #pragma unroll
            for (int i=0;i<4;i++){
                int row = wr + i*16 + lw;
                af[i][ks] = *(const bf16x8*)&As[row*64 + (((ks*4+quad) ^ (lw&7)))*8];
            }
            #pragma unroll
            for (int j=0;j<2;j++){
                int col = wc + j*16 + lw;
                ba[j][ks] = *(const bf16x8*)&Ba[col*64 + (((ks*4+quad) ^ (lw&7)))*8];
                bg[j][ks] = *(const bf16x8*)&Bg[col*64 + (((ks*4+quad) ^ (lw&7)))*8];
            }
        }
        #pragma unroll
        for (int ks=0; ks<2; ks++)
            #pragma unroll
            for (int i=0;i<4;i++)
                #pragma unroll
                for (int j=0;j<2;j++){
                    acca[i][j] = __builtin_amdgcn_mfma_f32_16x16x32_bf16(af[i][ks], ba[j][ks], acca[i][j], 0, 0, 0);
                    accg[i][j] = __builtin_amdgcn_mfma_f32_16x16x32_bf16(af[i][ks], bg[j][ks], accg[i][j], 0, 0, 0);
                }
        __syncthreads();
    }
    #pragma unroll
    for (int i=0;i<4;i++){
        #pragma unroll
        for (int j=0;j<2;j++){
            #pragma unroll
            for (int reg=0; reg<4; reg++){
                int row = r0 + wr + i*16 + quad*4 + reg;
                int col = j0 + wc + j*16 + lw;
                float a = acca[i][j][reg] + b1[col];
                float g = accg[i][j][reg] + b1[2048+col];
                float gl = 0.5f*g*(1.0f + erff(g*0.70710678118654752f));
                out[(size_t)row*DFFI + col] = f2bf(a*gl);
            }
        }
    }
}

// ---------------- flash-style bf16 MFMA attention (bf16 in/out) ----------------
// one block = (b, h, 64-query tile); strides in elements. scale applied post-QK.
__global__ __launch_bounds__(256) void attn_bf16(
        const short* __restrict__ q, const short* __restrict__ k,
        const short* __restrict__ v, short* __restrict__ o,
        int Nq, int Nk, int qstr, int kstr, float scale){
    __shared__ short Qs[64][72];
    __shared__ short Ks[64][72];
    __shared__ short Vt[64][72];   // [d][key]
    __shared__ short Ps[64][72];
    int qt = blockIdx.x & ((Nq>>6)-1);
    int h  = (blockIdx.x / (Nq>>6)) & 7;
    int b  = blockIdx.x / ((Nq>>6)*8);
    int tid = threadIdx.x;
    int w = tid >> 6, lane = tid & 63;
    int quad = lane >> 4, lw = lane & 15;
    int srow = tid >> 2, sseg = tid & 3;
    int q0 = qt*64;

    {
        const short* qp = q + (size_t)(b*Nq + q0 + srow)*qstr + h*64 + sseg*16;
        *(bf16x8*)&Qs[srow][sseg*16]   = *(const bf16x8*)qp;
        *(bf16x8*)&Qs[srow][sseg*16+8] = *(const bf16x8*)(qp+8);
    }
    __syncthreads();
    bf16x8 qf0 = *(const bf16x8*)&Qs[w*16 + lw][quad*8];
    bf16x8 qf1 = *(const bf16x8*)&Qs[w*16 + lw][32 + quad*8];

    f32x4 oacc[4] = {};
    float m_[4] = {-1e30f,-1e30f,-1e30f,-1e30f};
    float l_[4] = {0.f,0.f,0.f,0.f};

    int nkt = Nk >> 6;
    for (int kt = 0; kt < nkt; kt++){
        __syncthreads();
        {
            const short* kp = k + (size_t)(b*Nk + kt*64 + srow)*kstr + h*64 + sseg*16;
            *(bf16x8*)&Ks[srow][sseg*16]   = *(const bf16x8*)kp;
            *(bf16x8*)&Ks[srow][sseg*16+8] = *(const bf16x8*)(kp+8);
            const short* vp = v + (size_t)(b*Nk + kt*64 + srow)*kstr + h*64 + sseg*16;
            bf16x8 y0 = *(const bf16x8*)vp;
            bf16x8 y1 = *(const bf16x8*)(vp+8);
            #pragma unroll
            for (int i=0;i<8;i++) Vt[sseg*16+i][srow]   = y0[i];
            #pragma unroll
            for (int i=0;i<8;i++) Vt[sseg*16+8+i][srow] = y1[i];
        }
        __syncthreads();

        f32x4 s[4] = {};
        #pragma unroll
        for (int ct=0; ct<4; ct++){
            bf16x8 kf0 = *(const bf16x8*)&Ks[ct*16 + lw][quad*8];
            bf16x8 kf1 = *(const bf16x8*)&Ks[ct*16 + lw][32 + quad*8];
            s[ct] = __builtin_amdgcn_mfma_f32_16x16x32_bf16(qf0, kf0, s[ct], 0, 0, 0);
            s[ct] = __builtin_amdgcn_mfma_f32_16x16x32_bf16(qf1, kf1, s[ct], 0, 0, 0);
        }
        #pragma unroll
        for (int ct=0; ct<4; ct++)
            #pragma unroll
            for (int r=0;r<4;r++) s[ct][r] *= scale;

        float mx[4], alpha[4];
        #pragma unroll
        for (int r=0;r<4;r++){
            float mv = fmaxf(fmaxf(s[0][r], s[1][r]), fmaxf(s[2][r], s[3][r]));
            #pragma unroll
            for (int off=8; off>0; off>>=1) mv = fmaxf(mv, __shfl_xor(mv, off, 16));
            float mn = fmaxf(m_[r], mv);
            alpha[r] = __expf(m_[r] - mn);
            m_[r] = mn;
            mx[r] = mn;
        }
        float p[4][4];
        #pragma unroll
        for (int ct=0; ct<4; ct++)
            #pragma unroll
            for (int r=0;r<4;r++) p[ct][r] = __expf(s[ct][r] - mx[r]);
        #pragma unroll
        for (int r=0;r<4;r++){
            float sv = p[0][r]+p[1][r]+p[2][r]+p[3][r];
            #pragma unroll
            for (int off=8; off>0; off>>=1) sv += __shfl_xor(sv, off, 16);
            l_[r] = l_[r]*alpha[r] + sv;
        }
        #pragma unroll
        for (int ct=0; ct<4; ct++)
            #pragma unroll
            for (int r=0;r<4;r++)
                Ps[w*16 + quad*4 + r][ct*16 + lw] = f2bf(p[ct][r]);
        __asm__ volatile("s_waitcnt lgkmcnt(0)" ::: "memory");

        #pragma unroll
        for (int dt=0; dt<4; dt++)
            #pragma unroll
            for (int r=0;r<4;r++) oacc[dt][r] *= alpha[r];
        bf16x8 pf0 = *(const bf16x8*)&Ps[w*16 + lw][quad*8];
        bf16x8 pf1 = *(const bf16x8*)&Ps[w*16 + lw][32 + quad*8];
        #pragma unroll
        for (int dt=0; dt<4; dt++){
            bf16x8 vf0 = *(const bf16x8*)&Vt[dt*16 + lw][quad*8];
            bf16x8 vf1 = *(const bf16x8*)&Vt[dt*16 + lw][32 + quad*8];
            oacc[dt] = __builtin_amdgcn_mfma_f32_16x16x32_bf16(pf0, vf0, oacc[dt], 0, 0, 0);
            oacc[dt] = __builtin_amdgcn_mfma_f32_16x16x32_bf16(pf1, vf1, oacc[dt], 0, 0, 0);
        }
    }
    #pragma unroll
    for (int dt=0; dt<4; dt++){
        #pragma unroll
        for (int r=0;r<4;r++){
            int qi = q0 + w*16 + quad*4 + r;
            o[((size_t)(b*Nq + qi)*512 + h*64 + dt*16 + lw)] = f2bf(oacc[dt][r] / l_[r]);
        }
    }
}

extern "C" void kernel_launch(void* const* d_in, const int* in_sizes, int n_in,
                              void* d_out, int out_size, void* d_ws, size_t ws_size,
                              hipStream_t stream) {
    const float* x      = (const float*)d_in[0];
    const float* emb    = (const float*)d_in[1];
    const float* context= (const float*)d_in[2];
    const float* w_emb  = (const float*)d_in[3];
    const float* b_emb  = (const float*)d_in[4];
    const float* gn_g   = (const float*)d_in[5];
    const float* gn_b   = (const float*)d_in[6];
    const float* conv_w = (const float*)d_in[7];
    const float* conv_b = (const float*)d_in[8];
    const float* a1_wq  = (const float*)d_in[9];
    const float* a1_wk  = (const float*)d_in[10];
    const float* a1_wv  = (const float*)d_in[11];
    const float* a1_wo  = (const float*)d_in[12];
    const float* a1_bo  = (const float*)d_in[13];
    const float* a2_wq  = (const float*)d_in[14];
    const float* a2_wk  = (const float*)d_in[15];
    const float* a2_wv  = (const float*)d_in[16];
    const float* a2_wo  = (const float*)d_in[17];
    const float* a2_bo  = (const float*)d_in[18];
    const float* ln1_g  = (const float*)d_in[19];
    const float* ln1_b  = (const float*)d_in[20];
    const float* ln2_g  = (const float*)d_in[21];
    const float* ln2_b  = (const float*)d_in[22];
    const float* ln3_g  = (const float*)d_in[23];
    const float* ln3_b  = (const float*)d_in[24];
    const float* ff_w1  = (const float*)d_in[25];
    const float* ff_b1  = (const float*)d_in[26];
    const float* ff_w2  = (const float*)d_in[27];
    const float* ff_b2  = (const float*)d_in[28];
    float* out = (float*)d_out;

    char* base = (char*)d_ws;
    float* SS    = (float*)base;                     // 8192
    float* STATS = SS + 8192;                        // 512
    float* F0    = (float*)(base + 65536);           // [8192,512] f32 residual stream
    float* F1    = F0 + 4194304;
    short* WB    = (short*)(F1 + 4194304);           // bf16 weights
    short* convW = WB;                               // 512x512
    short* qkvW  = WB + 262144;                      // 1536x512 (q,k,v)
    short* wo1W  = WB + 1048576;                     // 512x512
    short* a2qW  = WB + 1310720;                     // 512x512
    short* a2kvW = WB + 1572864;                     // 1024x512 (k,v)
    short* wo2W  = WB + 2097152;                     // 512x512
    short* ffw1W = WB + 2359296;                     // 4096x512
    short* ffw2W = WB + 4456448;                     // 512x2048
    short* CTXb  = WB + 5505024;                     // [2048,512]
    short* L0    = CTXb + 1048576;                   // [8192,512] bf16 (LN / mod_act out)
    short* Q0    = L0 + 4194304;                     // [8192,1536] qkv packed
    short* AO    = Q0 + 12582912;                    // [8192,512] attn out
    short* A2Q   = Q0;                               // [8192,512] (reuse)
    short* A2KV  = Q0 + 4194304;                     // [2048,1024] (reuse)
    short* ACT2  = Q0;                               // [8192,2048] spans Q0+AO (reuse)

    dim3 tb(32,8);

    // ---- weight conversion (bf16) ----
    cvt<<<128,256,0,stream>>>(conv_w, convW, 262144);
    cvt<<<128,256,0,stream>>>(a1_wq, qkvW,          262144);
    cvt<<<128,256,0,stream>>>(a1_wk, qkvW+262144,   262144);
    cvt<<<128,256,0,stream>>>(a1_wv, qkvW+524288,   262144);
    cvt<<<128,256,0,stream>>>(a1_wo, wo1W, 262144);
    cvt<<<128,256,0,stream>>>(a2_wq, a2qW, 262144);
    cvt<<<128,256,0,stream>>>(a2_wk, a2kvW,         262144);
    cvt<<<128,256,0,stream>>>(a2_wv, a2kvW+262144,  262144);
    cvt<<<128,256,0,stream>>>(a2_wo, wo2W, 262144);
    cvt<<<1024,256,0,stream>>>(ff_w1, ffw1W, 2097152);
    cvt<<<512,256,0,stream>>>(ff_w2, ffw2W, 1048576);

    // ---- residual conv branch ----
    emb_gemm<<<32,256,0,stream>>>(emb, w_emb, b_emb, SS);
    gn_stats<<<256,256,0,stream>>>(x, STATS);
    mod_act<<<dim3(32,16,8), tb, 0, stream>>>(x, STATS, gn_g, gn_b, SS, L0);
    transpose_ctx<<<dim3(8,16,8), tb, 0, stream>>>(context, CTXb);
    gemm_bb<<<dim3(64,4),256,0,stream>>>(L0, convW, conv_b, x, F0, nullptr, 512, 512, 512, 2);   // xt0 = F0

    // ---- self attention ----
    ln_rows<<<8192,256,0,stream>>>(F0, ln1_g, ln1_b, L0);
    gemm_bb<<<dim3(64,12),256,0,stream>>>(L0, qkvW, nullptr, nullptr, nullptr, Q0, 512, 1536, 1536, 0);
    attn_bf16<<<1024,256,0,stream>>>(Q0, Q0+512, Q0+1024, AO, 1024, 1024, 1536, 1536, 0.125f);
    gemm_bb<<<dim3(64,4),256,0,stream>>>(AO, wo1W, a1_bo, F0, F1, nullptr, 512, 512, 512, 1);    // xt1 = F1

    // ---- cross attention ----
    ln_rows<<<8192,256,0,stream>>>(F1, ln2_g, ln2_b, L0);
    gemm_bb<<<dim3(64,4),256,0,stream>>>(L0, a2qW, nullptr, nullptr, nullptr, A2Q, 512, 512, 512, 0);
    gemm_bb<<<dim3(16,8),256,0,stream>>>(CTXb, a2kvW, nullptr, nullptr, nullptr, A2KV, 512, 1024, 1024, 0);
    attn_bf16<<<1024,256,0,stream>>>(A2Q, A2KV, A2KV+512, AO, 1024, 256, 512, 1024, 0.125f);
    gemm_bb<<<dim3(64,4),256,0,stream>>>(AO, wo2W, a2_bo, F1, F0, nullptr, 512, 512, 512, 1);    // xt2 = F0

    // ---- GEGLU FF ----
    ln_rows<<<8192,256,0,stream>>>(F0, ln3_g, ln3_b, L0);
    ff1_geglu_bb<<<dim3(64,32),256,0,stream>>>(L0, ffw1W, ff_b1, ACT2);
    gemm_bb<<<dim3(64,4),256,0,stream>>>(ACT2, ffw2W, ff_b2, F0, F1, nullptr, 2048, 512, 512, 1);
    transpose_out<<<dim3(32,16,8), tb, 0, stream>>>(F1, out);
}

// Round 4
// 578.622 us; speedup vs baseline: 12.4342x; 1.0722x over previous
//
#include <hip/hip_runtime.h>
#include <math.h>

#define NB 8
#define CDIM 512
#define NT 1024
#define MT 256
#define DFFI 2048   // GEGLU inner half

typedef short bf16x8 __attribute__((ext_vector_type(8)));
typedef float f32x4 __attribute__((ext_vector_type(4)));

__device__ __forceinline__ float sigmoidf_(float v){ return 1.0f/(1.0f+__expf(-v)); }

__device__ __forceinline__ short f2bf(float f){
    union { float f; unsigned u; } v; v.f = f;
    unsigned r = v.u + 0x7FFFu + ((v.u >> 16) & 1u);
    return (short)(r >> 16);
}

#define GLDS(gp, lp) __builtin_amdgcn_global_load_lds( \
    (const __attribute__((address_space(1))) void*)(gp), \
    (__attribute__((address_space(3))) void*)(lp), 16, 0, 0)

// ---------------- fused f32 -> bf16 weight conversion (single launch) ----------------
// WB layout (shorts): a1wq 0, a1wk 262144, a1wv 524288, a1wo 786432, a2wq 1048576,
// a2wk 1310720, a2wv 1572864, a2wo 1835008, ffw1 2097152, ffw2 4194304, conv 5242880.
__global__ void cvt_all(const float* __restrict__ a1wq, const float* __restrict__ a1wk,
                        const float* __restrict__ a1wv, const float* __restrict__ a1wo,
                        const float* __restrict__ a2wq, const float* __restrict__ a2wk,
                        const float* __restrict__ a2wv, const float* __restrict__ a2wo,
                        const float* __restrict__ ffw1, const float* __restrict__ ffw2,
                        const float* __restrict__ convw, short* __restrict__ WB){
    int e = (blockIdx.x*256 + threadIdx.x)*8;
    if (e >= 5505024) return;
    const float* src; int off;
    if (e < 2097152){
        const float* tbl[8] = {a1wq,a1wk,a1wv,a1wo,a2wq,a2wk,a2wv,a2wo};
        src = tbl[e >> 18]; off = e & 262143;
    } else if (e < 4194304){ src = ffw1; off = e - 2097152; }
    else if (e < 5242880){ src = ffw2; off = e - 4194304; }
    else { src = convw; off = e - 5242880; }
    float4 x0 = ((const float4*)(src+off))[0], x1 = ((const float4*)(src+off))[1];
    bf16x8 v;
    v[0]=f2bf(x0.x); v[1]=f2bf(x0.y); v[2]=f2bf(x0.z); v[3]=f2bf(x0.w);
    v[4]=f2bf(x1.x); v[5]=f2bf(x1.y); v[6]=f2bf(x1.z); v[7]=f2bf(x1.w);
    *(bf16x8*)(WB + e) = v;
}

// ---------------- small elementwise / norm kernels ----------------

__global__ void emb_gemm(const float* __restrict__ emb, const float* __restrict__ w,
                         const float* __restrict__ bias, float* __restrict__ out){
    int idx = blockIdx.x*256 + threadIdx.x;   // 8*1024 total
    int b = idx >> 10, o = idx & 1023;
    const float* e = emb + b*128;
    const float* wr = w + (size_t)o*128;
    float acc = 0.f;
    for (int i=0;i<128;i++){ float ev=e[i]; acc += (ev*sigmoidf_(ev))*wr[i]; }
    out[idx] = acc + bias[o];
}

__global__ void gn_stats(const float* __restrict__ x, float* __restrict__ stats){
    int bg = blockIdx.x;               // b*32+g
    const float* base = x + (size_t)bg*16*NT;
    float s=0.f, sq=0.f;
    for (int i=threadIdx.x; i<16*NT; i+=256){ float v = base[i]; s+=v; sq+=v*v; }
    __shared__ float rs[256], rq[256];
    rs[threadIdx.x]=s; rq[threadIdx.x]=sq; __syncthreads();
    for (int st=128; st>0; st>>=1){
        if (threadIdx.x<st){ rs[threadIdx.x]+=rs[threadIdx.x+st]; rq[threadIdx.x]+=rq[threadIdx.x+st]; }
        __syncthreads();
    }
    if (threadIdx.x==0){
        float mu = rs[0]/(16.f*NT);
        float var = rq[0]/(16.f*NT) - mu*mu;
        stats[2*bg] = mu; stats[2*bg+1] = rsqrtf(var + 1e-6f);
    }
}

__global__ void mod_act(const float* __restrict__ x, const float* __restrict__ stats,
                        const float* __restrict__ gg, const float* __restrict__ gb,
                        const float* __restrict__ ss, short* __restrict__ act_t){
    __shared__ float tile[32][33];
    int n0 = blockIdx.x*32, c0 = blockIdx.y*32, b = blockIdx.z;
    int tx = threadIdx.x, ty = threadIdx.y;
    #pragma unroll
    for (int k=0;k<4;k++){
        int c = c0 + ty + k*8;
        tile[ty+k*8][tx] = x[((size_t)(b*CDIM+c))*NT + n0 + tx];
    }
    __syncthreads();
    #pragma unroll
    for (int k=0;k<4;k++){
        int c = c0 + tx, n = n0 + ty + k*8;
        float raw = tile[tx][ty+k*8];
        int gi = b*32 + (c>>4);
        float v = (raw - stats[2*gi]) * stats[2*gi+1] * gg[c] + gb[c];
        v = v * (1.f + ss[b*1024 + c]) + ss[b*1024 + 512 + c];
        act_t[((size_t)(b*NT+n))*CDIM + c] = f2bf(v * sigmoidf_(v));
    }
}

__global__ void ln_rows(const float* __restrict__ in, const float* __restrict__ g,
                        const float* __restrict__ bta, short* __restrict__ out){
    int row = blockIdx.x;
    const float* base = in + (size_t)row*CDIM;
    int t = threadIdx.x;
    float v0 = base[t], v1 = base[t+256];
    __shared__ float rs[256], rq[256];
    rs[t]=v0+v1; rq[t]=v0*v0+v1*v1; __syncthreads();
    for (int st=128; st>0; st>>=1){
        if (t<st){ rs[t]+=rs[t+st]; rq[t]+=rq[t+st]; }
        __syncthreads();
    }
    float mu = rs[0]*(1.f/512.f);
    float var = rq[0]*(1.f/512.f) - mu*mu;
    float rstd = rsqrtf(var + 1e-5f);
    out[(size_t)row*CDIM + t]     = f2bf((v0-mu)*rstd*g[t]+bta[t]);
    out[(size_t)row*CDIM + t+256] = f2bf((v1-mu)*rstd*g[t+256]+bta[t+256]);
}

__global__ void transpose_ctx(const float* __restrict__ in, short* __restrict__ out){
    __shared__ float tile[32][33];
    int m0 = blockIdx.x*32, c0 = blockIdx.y*32, b = blockIdx.z;
    int tx=threadIdx.x, ty=threadIdx.y;
    #pragma unroll
    for (int k=0;k<4;k++){
        int c = c0+ty+k*8;
        tile[ty+k*8][tx] = in[((size_t)(b*512+c))*MT + m0+tx];
    }
    __syncthreads();
    #pragma unroll
    for (int k=0;k<4;k++){
        int m = m0+ty+k*8, c = c0+tx;
        out[((size_t)(b*MT+m))*512 + c] = f2bf(tile[tx][ty+k*8]);
    }
}

__global__ void transpose_out(const float* __restrict__ in, float* __restrict__ out){
    __shared__ float tile[32][33];
    int n0 = blockIdx.x*32, c0 = blockIdx.y*32, b=blockIdx.z;
    int tx=threadIdx.x, ty=threadIdx.y;
    #pragma unroll
    for (int k=0;k<4;k++){
        int n = n0+ty+k*8;
        tile[ty+k*8][tx] = in[((size_t)(b*NT+n))*512 + c0+tx];
    }
    __syncthreads();
    #pragma unroll
    for (int k=0;k<4;k++){
        int c = c0+ty+k*8, n = n0+tx;
        out[((size_t)(b*512+c))*NT + n] = tile[tx][ty+k*8];
    }
}

// ---------------- m97-style bf16 GEMM: 128x128 tile, BK=64, global_load_lds ----------------
__global__ __launch_bounds__(256) void gemm_bb(
        const short* __restrict__ A, const short* __restrict__ W,
        const float* __restrict__ bias, const float* __restrict__ res,
        float* __restrict__ outf, short* __restrict__ outb,
        int K, int O, int ostr, int resmode){
    __shared__ short As[128*64];
    __shared__ short Bs[128*64];
    int r0 = blockIdx.x*128, o0 = blockIdx.y*128;
    int tid = threadIdx.x, w = tid>>6, lane = tid&63;
    int quad = lane>>4, lw = lane&15;
    int g_row = lane>>3, g_s = lane&7;
    int sseg = g_s ^ g_row;
    int wr = (w&1)*64, wc = (w>>1)*64;
    f32x4 acc[4][4] = {};
    for (int k0 = 0; k0 < K; k0 += 64){
        #pragma unroll
        for (int j=0;j<4;j++){
            int row = w*32 + j*8 + g_row;
            GLDS(A + (size_t)(r0+row)*K + k0 + sseg*8, As + (w*32+j*8)*64);
        }
        #pragma unroll
        for (int j=0;j<4;j++){
            int row = w*32 + j*8 + g_row;
            GLDS(W + (size_t)(o0+row)*K + k0 + sseg*8, Bs + (w*32+j*8)*64);
        }
        __syncthreads();
        bf16x8 af[4][2], bf[4][2];
        #pragma unroll
        for (int ks=0; ks<2; ks++){
            #pragma unroll
            for (int i=0;i<4;i++){
                int row = wr + i*16 + lw;
                af[i][ks] = *(const bf16x8*)&As[row*64 + (((ks*4+quad) ^ (lw&7)))*8];
                int col = wc + i*16 + lw;
                bf[i][ks] = *(const bf16x8*)&Bs[col*64 + (((ks*4+quad) ^ (lw&7)))*8];
            }
        }
        #pragma unroll
        for (int ks=0; ks<2; ks++)
            #pragma unroll
            for (int i=0;i<4;i++)
                #pragma unroll
                for (int j=0;j<4;j++)
                    acc[i][j] = __builtin_amdgcn_mfma_f32_16x16x32_bf16(af[i][ks], bf[j][ks], acc[i][j], 0, 0, 0);
        __syncthreads();
    }
    #pragma unroll
    for (int i=0;i<4;i++){
        #pragma unroll
        for (int j=0;j<4;j++){
            #pragma unroll
            for (int reg=0; reg<4; reg++){
                int row = r0 + wr + i*16 + quad*4 + reg;
                int col = o0 + wc + j*16 + lw;
                float v = acc[i][j][reg];
                if (bias) v += bias[col];
                if (resmode==1) v += res[(size_t)row*O + col];
                else if (resmode==2){
                    int b = row >> 10, n = row & 1023;
                    v += res[((size_t)(b*CDIM+col))*NT + n];
                }
                if (outf) outf[(size_t)row*ostr + col] = v;
                else      outb[(size_t)row*ostr + col] = f2bf(v);
            }
        }
    }
}

// ---------------- FF1 fused GEGLU, 128x64 tile (x2 gates), BK=64 ----------------
__global__ __launch_bounds__(256) void ff1_geglu_bb(
        const short* __restrict__ A, const short* __restrict__ W,
        const float* __restrict__ b1, short* __restrict__ out){
    __shared__ short As[128*64];
    __shared__ short Ba[64*64];
    __shared__ short Bg[64*64];
    int r0 = blockIdx.x*128, j0 = blockIdx.y*64;
    int tid = threadIdx.x, w = tid>>6, lane = tid&63;
    int quad = lane>>4, lw = lane&15;
    int g_row = lane>>3, g_s = lane&7;
    int sseg = g_s ^ g_row;
    int wr = (w&1)*64, wc = (w>>1)*32;
    f32x4 acca[4][2] = {}, accg[4][2] = {};
    for (int k0 = 0; k0 < 512; k0 += 64){
        #pragma unroll
        for (int j=0;j<4;j++){
            int row = w*32 + j*8 + g_row;
            GLDS(A + (size_t)(r0+row)*512 + k0 + sseg*8, As + (w*32+j*8)*64);
        }
        #pragma unroll
        for (int j=0;j<2;j++){
            int row = w*16 + j*8 + g_row;
            GLDS(W + (size_t)(j0+row)*512 + k0 + sseg*8, Ba + (w*16+j*8)*64);
            GLDS(W + (size_t)(2048+j0+row)*512 + k0 + sseg*8, Bg + (w*16+j*8)*64);
        }
        __syncthreads();
        bf16x8 af[4][2], ba[2][2], bg[2][2];
        #pragma unroll
        for (int ks=0; ks<2; ks++){
            #pragma unroll
            for (int i=0;i<4;i++){
                int row = wr + i*16 + lw;
                af[i][ks] = *(const bf16x8*)&As[row*64 + (((ks*4+quad) ^ (lw&7)))*8];
            }
            #pragma unroll
            for (int j=0;j<2;j++){
                int col = wc + j*16 + lw;
                ba[j][ks] = *(const bf16x8*)&Ba[col*64 + (((ks*4+quad) ^ (lw&7)))*8];
                bg[j][ks] = *(const bf16x8*)&Bg[col*64 + (((ks*4+quad) ^ (lw&7)))*8];
            }
        }
        #pragma unroll
        for (int ks=0; ks<2; ks++)
            #pragma unroll
            for (int i=0;i<4;i++)
                #pragma unroll
                for (int j=0;j<2;j++){
                    acca[i][j] = __builtin_amdgcn_mfma_f32_16x16x32_bf16(af[i][ks], ba[j][ks], acca[i][j], 0, 0, 0);
                    accg[i][j] = __builtin_amdgcn_mfma_f32_16x16x32_bf16(af[i][ks], bg[j][ks], accg[i][j], 0, 0, 0);
                }
        __syncthreads();
    }
    #pragma unroll
    for (int i=0;i<4;i++){
        #pragma unroll
        for (int j=0;j<2;j++){
            #pragma unroll
            for (int reg=0; reg<4; reg++){
                int row = r0 + wr + i*16 + quad*4 + reg;
                int col = j0 + wc + j*16 + lw;
                float a = acca[i][j][reg] + b1[col];
                float g = accg[i][j][reg] + b1[2048+col];
                float gl = 0.5f*g*(1.0f + erff(g*0.70710678118654752f));
                out[(size_t)row*DFFI + col] = f2bf(a*gl);
            }
        }
    }
}

// ---------------- flash attention: GLDS staging, global V^T, no-max softmax ----------------
// blockIdx.x = qt*64 + b*8 + h  (XCD swizzle: all q-tiles of one (b,h) on one XCD)
// q: [b*Nq+n, qstr] bf16; k: [b*Nk+m, kstr]; vt: [h*64+d, vtstr] with token col = b*Nk+m.
__global__ __launch_bounds__(256) void attn_fa(
        const short* __restrict__ q, const short* __restrict__ k,
        const short* __restrict__ vt, short* __restrict__ o,
        int Nq, int Nk, int qstr, int kstr, int vtstr, float sc_log2e){
    __shared__ short Ks[64*64];
    __shared__ short Vs[64*64];
    __shared__ short QP[64*64];   // Qs (start) then Ps (loop) — both wave-local rows
    int bh = blockIdx.x & 63;
    int qt = blockIdx.x >> 6;
    int b = bh >> 3, h = bh & 7;
    int tid = threadIdx.x, w = tid>>6, lane = tid&63;
    int quad = lane>>4, lw = lane&15;
    int lrow = lane>>3, lg = (lane&7) ^ (lane>>3);   // GLDS lane -> row-in-8, swizzled 16B group
    int q0 = qt*64;

    // stage Q (swizzled groups, GLDS)
    #pragma unroll
    for (int t=0;t<2;t++){
        int row = w*16 + t*8 + lrow;
        GLDS(q + (size_t)(b*Nq + q0 + row)*qstr + h*64 + lg*8, QP + (w*16+t*8)*64);
    }
    __syncthreads();
    bf16x8 qf[2];
    {
        int r = w*16 + lw;
        qf[0] = *(const bf16x8*)&QP[r*64 + (( quad      ^ (r&7))*8)];
        qf[1] = *(const bf16x8*)&QP[r*64 + (((quad+4) ^ (r&7))*8)];
    }

    f32x4 oacc[4] = {};
    f32x4 accl = {};
    bf16x8 ones;
    #pragma unroll
    for (int i=0;i<8;i++) ones[i] = (short)0x3F80;   // bf16 1.0

    int nkt = Nk >> 6;
    for (int kt = 0; kt < nkt; kt++){
        __syncthreads();   // protect Ks/Vs from previous iteration's readers
        #pragma unroll
        for (int t=0;t<2;t++){
            int row = w*16 + t*8 + lrow;
            GLDS(k  + (size_t)(b*Nk + kt*64 + row)*kstr + h*64 + lg*8, Ks + (w*16+t*8)*64);
            GLDS(vt + (size_t)(h*64 + row)*vtstr + b*Nk + kt*64 + lg*8, Vs + (w*16+t*8)*64);
        }
        __syncthreads();

        // S = Q.K^T
        f32x4 s[4] = {};
        #pragma unroll
        for (int ct=0;ct<4;ct++){
            int r = ct*16 + lw;
            bf16x8 kf0 = *(const bf16x8*)&Ks[r*64 + (( quad      ^ (r&7))*8)];
            bf16x8 kf1 = *(const bf16x8*)&Ks[r*64 + (((quad+4) ^ (r&7))*8)];
            s[ct] = __builtin_amdgcn_mfma_f32_16x16x32_bf16(qf[0], kf0, s[ct], 0,0,0);
            s[ct] = __builtin_amdgcn_mfma_f32_16x16x32_bf16(qf[1], kf1, s[ct], 0,0,0);
        }

        // P = exp2(S*scale*log2e)  (no max shift; |S*scale| << 88)
        // store to Ps with quad-rotated column-group swizzle (conflict-free b16 writes)
        #pragma unroll
        for (int ct=0;ct<4;ct++){
            int colb = (((ct+quad)&3)*16) + lw;
            #pragma unroll
            for (int r=0;r<4;r++){
                float p = exp2f(s[ct][r]*sc_log2e);
                union { float f; unsigned u; } uv; uv.f = p;
                QP[(w*16 + quad*4 + r)*64 + colb] = (short)(uv.u >> 16);  // truncate: l uses same bf16 P
            }
        }
        __asm__ volatile("s_waitcnt lgkmcnt(0)" ::: "memory");  // wave-local RAW on QP

        bf16x8 pf[2];
        {
            int r = w*16 + lw;
            int rot = (lw>>2)&3;
            pf[0] = *(const bf16x8*)&QP[r*64 + (((    (quad>>1) + rot)&3)*16) + (quad&1)*8];
            pf[1] = *(const bf16x8*)&QP[r*64 + (((2 + (quad>>1) + rot)&3)*16) + (quad&1)*8];
        }
        // l += P.1 (ones-MFMA: replaces cross-lane sum shuffles)
        accl = __builtin_amdgcn_mfma_f32_16x16x32_bf16(pf[0], ones, accl, 0,0,0);
        accl = __builtin_amdgcn_mfma_f32_16x16x32_bf16(pf[1], ones, accl, 0,0,0);
        // O += P.V
        #pragma unroll
        for (int dt=0; dt<4; dt++){
            int r = dt*16 + lw;
            bf16x8 vf0 = *(const bf16x8*)&Vs[r*64 + (( quad      ^ (r&7))*8)];
            bf16x8 vf1 = *(const bf16x8*)&Vs[r*64 + (((quad+4) ^ (r&7))*8)];
            oacc[dt] = __builtin_amdgcn_mfma_f32_16x16x32_bf16(pf[0], vf0, oacc[dt], 0,0,0);
            oacc[dt] = __builtin_amdgcn_mfma_f32_16x16x32_bf16(pf[1], vf1, oacc[dt], 0,0,0);
        }
    }
    float inv[4];
    #pragma unroll
    for (int r=0;r<4;r++) inv[r] = 1.0f/accl[r];
    #pragma unroll
    for (int dt=0; dt<4; dt++){
        #pragma unroll
        for (int r=0;r<4;r++){
            int qi = q0 + w*16 + quad*4 + r;
            o[(size_t)(b*Nq + qi)*512 + h*64 + dt*16 + lw] = f2bf(oacc[dt][r]*inv[r]);
        }
    }
}

extern "C" void kernel_launch(void* const* d_in, const int* in_sizes, int n_in,
                              void* d_out, int out_size, void* d_ws, size_t ws_size,
                              hipStream_t stream) {
    const float* x      = (const float*)d_in[0];
    const float* emb    = (const float*)d_in[1];
    const float* context= (const float*)d_in[2];
    const float* w_emb  = (const float*)d_in[3];
    const float* b_emb  = (const float*)d_in[4];
    const float* gn_g   = (const float*)d_in[5];
    const float* gn_b   = (const float*)d_in[6];
    const float* conv_w = (const float*)d_in[7];
    const float* conv_b = (const float*)d_in[8];
    const float* a1_wq  = (const float*)d_in[9];
    const float* a1_wk  = (const float*)d_in[10];
    const float* a1_wv  = (const float*)d_in[11];
    const float* a1_wo  = (const float*)d_in[12];
    const float* a1_bo  = (const float*)d_in[13];
    const float* a2_wq  = (const float*)d_in[14];
    const float* a2_wk  = (const float*)d_in[15];
    const float* a2_wv  = (const float*)d_in[16];
    const float* a2_wo  = (const float*)d_in[17];
    const float* a2_bo  = (const float*)d_in[18];
    const float* ln1_g  = (const float*)d_in[19];
    const float* ln1_b  = (const float*)d_in[20];
    const float* ln2_g  = (const float*)d_in[21];
    const float* ln2_b  = (const float*)d_in[22];
    const float* ln3_g  = (const float*)d_in[23];
    const float* ln3_b  = (const float*)d_in[24];
    const float* ff_w1  = (const float*)d_in[25];
    const float* ff_b1  = (const float*)d_in[26];
    const float* ff_w2  = (const float*)d_in[27];
    const float* ff_b2  = (const float*)d_in[28];
    float* out = (float*)d_out;

    char* base = (char*)d_ws;
    float* SS    = (float*)base;                 // 8192 f
    float* STATS = SS + 8192;                    // 512 f
    float* F0    = (float*)(base + 65536);       // [8192,512] f32 residual
    float* F1    = F0 + 4194304;
    short* WB    = (short*)(F1 + 4194304);       // bf16 weights, 5505024 shorts
    short* qkW   = WB;                           // [1024,512]: a1_wq, a1_wk
    short* vW    = WB + 524288;                  // [512,512]
    short* wo1W  = WB + 786432;
    short* a2qW  = WB + 1048576;
    short* a2kW  = WB + 1310720;
    short* a2vW  = WB + 1572864;
    short* wo2W  = WB + 1835008;
    short* ffw1W = WB + 2097152;                 // [4096,512]
    short* ffw2W = WB + 4194304;                 // [512,2048]
    short* convW = WB + 5242880;
    short* CTXb  = WB + 5505024;                 // [2048,512]
    short* L0    = CTXb + 1048576;               // [8192,512]
    short* BIG   = L0 + 4194304;                 // 16777216 shorts, multi-purpose
    short* Q0    = BIG;                          // [8192,1024]: q | k
    short* VT1   = BIG + 8388608;                // [512,8192] V^T (self)
    short* AO    = BIG + 12582912;               // [8192,512]
    short* A2Q   = BIG;                          // [8192,512]
    short* K2    = BIG + 4194304;                // [2048,512]
    short* VT2   = BIG + 5242880;                // [512,2048]
    short* ACT2  = BIG;                          // [8192,2048]

    dim3 tb(32,8);
    const float SCL2E = 0.125f * 1.4426950408889634f;

    // ---- weights -> bf16 (one launch) ----
    cvt_all<<<2688,256,0,stream>>>(a1_wq,a1_wk,a1_wv,a1_wo,a2_wq,a2_wk,a2_wv,a2_wo,
                                   ff_w1,ff_w2,conv_w, WB);

    // ---- residual conv branch ----
    emb_gemm<<<32,256,0,stream>>>(emb, w_emb, b_emb, SS);
    gn_stats<<<256,256,0,stream>>>(x, STATS);
    mod_act<<<dim3(32,16,8), tb, 0, stream>>>(x, STATS, gn_g, gn_b, SS, L0);
    transpose_ctx<<<dim3(8,16,8), tb, 0, stream>>>(context, CTXb);
    gemm_bb<<<dim3(64,4),256,0,stream>>>(L0, convW, conv_b, x, F0, nullptr, 512, 512, 512, 2);  // xt0=F0

    // ---- self attention ----
    ln_rows<<<8192,256,0,stream>>>(F0, ln1_g, ln1_b, L0);
    gemm_bb<<<dim3(64,8),256,0,stream>>>(L0, qkW, nullptr, nullptr, nullptr, Q0, 512, 1024, 1024, 0);
    gemm_bb<<<dim3(4,64),256,0,stream>>>(vW, L0, nullptr, nullptr, nullptr, VT1, 512, 8192, 8192, 0); // V^T
    attn_fa<<<1024,256,0,stream>>>(Q0, Q0+512, VT1, AO, 1024, 1024, 1024, 1024, 8192, SCL2E);
    gemm_bb<<<dim3(64,4),256,0,stream>>>(AO, wo1W, a1_bo, F0, F1, nullptr, 512, 512, 512, 1);   // xt1=F1

    // ---- cross attention ----
    ln_rows<<<8192,256,0,stream>>>(F1, ln2_g, ln2_b, L0);
    gemm_bb<<<dim3(64,4),256,0,stream>>>(L0, a2qW, nullptr, nullptr, nullptr, A2Q, 512, 512, 512, 0);
    gemm_bb<<<dim3(16,4),256,0,stream>>>(CTXb, a2kW, nullptr, nullptr, nullptr, K2, 512, 512, 512, 0);
    gemm_bb<<<dim3(4,16),256,0,stream>>>(a2vW, CTXb, nullptr, nullptr, nullptr, VT2, 512, 2048, 2048, 0); // V^T
    attn_fa<<<1024,256,0,stream>>>(A2Q, K2, VT2, AO, 1024, 256, 512, 512, 2048, SCL2E);
    gemm_bb<<<dim3(64,4),256,0,stream>>>(AO, wo2W, a2_bo, F1, F0, nullptr, 512, 512, 512, 1);   // xt2=F0

    // ---- GEGLU FF ----
    ln_rows<<<8192,256,0,stream>>>(F0, ln3_g, ln3_b, L0);
    ff1_geglu_bb<<<dim3(64,32),256,0,stream>>>(L0, ffw1W, ff_b1, ACT2);
    gemm_bb<<<dim3(64,4),256,0,stream>>>(ACT2, ffw2W, ff_b2, F0, F1, nullptr, 2048, 512, 512, 1);
    transpose_out<<<dim3(32,16,8), tb, 0, stream>>>(F1, out);
}

// Round 5
// 466.992 us; speedup vs baseline: 15.4065x; 1.2390x over previous
//
#include <hip/hip_runtime.h>
#include <math.h>

#define NB 8
#define CDIM 512
#define NT 1024
#define MT 256
#define DFFI 2048   // GEGLU inner half

typedef short bf16x8 __attribute__((ext_vector_type(8)));
typedef float f32x4 __attribute__((ext_vector_type(4)));

__device__ __forceinline__ float sigmoidf_(float v){ return 1.0f/(1.0f+__expf(-v)); }

__device__ __forceinline__ short f2bf(float f){
    union { float f; unsigned u; } v; v.f = f;
    unsigned r = v.u + 0x7FFFu + ((v.u >> 16) & 1u);
    return (short)(r >> 16);
}

#define GLDS(gp, lp) __builtin_amdgcn_global_load_lds( \
    (const __attribute__((address_space(1))) void*)(gp), \
    (__attribute__((address_space(3))) void*)(lp), 16, 0, 0)

// ---------------- fused f32 -> bf16 weight conversion (single launch) ----------------
__global__ void cvt_all(const float* __restrict__ a1wq, const float* __restrict__ a1wk,
                        const float* __restrict__ a1wv, const float* __restrict__ a1wo,
                        const float* __restrict__ a2wq, const float* __restrict__ a2wk,
                        const float* __restrict__ a2wv, const float* __restrict__ a2wo,
                        const float* __restrict__ ffw1, const float* __restrict__ ffw2,
                        const float* __restrict__ convw, short* __restrict__ WB){
    int e = (blockIdx.x*256 + threadIdx.x)*8;
    if (e >= 5505024) return;
    const float* src; int off;
    if (e < 2097152){
        const float* tbl[8] = {a1wq,a1wk,a1wv,a1wo,a2wq,a2wk,a2wv,a2wo};
        src = tbl[e >> 18]; off = e & 262143;
    } else if (e < 4194304){ src = ffw1; off = e - 2097152; }
    else if (e < 5242880){ src = ffw2; off = e - 4194304; }
    else { src = convw; off = e - 5242880; }
    float4 x0 = ((const float4*)(src+off))[0], x1 = ((const float4*)(src+off))[1];
    bf16x8 v;
    v[0]=f2bf(x0.x); v[1]=f2bf(x0.y); v[2]=f2bf(x0.z); v[3]=f2bf(x0.w);
    v[4]=f2bf(x1.x); v[5]=f2bf(x1.y); v[6]=f2bf(x1.z); v[7]=f2bf(x1.w);
    *(bf16x8*)(WB + e) = v;
}

// ---------------- small elementwise / norm kernels ----------------

__global__ void emb_gemm(const float* __restrict__ emb, const float* __restrict__ w,
                         const float* __restrict__ bias, float* __restrict__ out){
    int idx = blockIdx.x*256 + threadIdx.x;   // 8*1024 total
    int b = idx >> 10, o = idx & 1023;
    const float* e = emb + b*128;
    const float* wr = w + (size_t)o*128;
    float acc = 0.f;
    for (int i=0;i<128;i++){ float ev=e[i]; acc += (ev*sigmoidf_(ev))*wr[i]; }
    out[idx] = acc + bias[o];
}

__global__ void gn_stats(const float* __restrict__ x, float* __restrict__ stats){
    int bg = blockIdx.x;               // b*32+g
    const float* base = x + (size_t)bg*16*NT;
    float s=0.f, sq=0.f;
    for (int i=threadIdx.x; i<16*NT; i+=256){ float v = base[i]; s+=v; sq+=v*v; }
    __shared__ float rs[256], rq[256];
    rs[threadIdx.x]=s; rq[threadIdx.x]=sq; __syncthreads();
    for (int st=128; st>0; st>>=1){
        if (threadIdx.x<st){ rs[threadIdx.x]+=rs[threadIdx.x+st]; rq[threadIdx.x]+=rq[threadIdx.x+st]; }
        __syncthreads();
    }
    if (threadIdx.x==0){
        float mu = rs[0]/(16.f*NT);
        float var = rq[0]/(16.f*NT) - mu*mu;
        stats[2*bg] = mu; stats[2*bg+1] = rsqrtf(var + 1e-6f);
    }
}

__global__ void mod_act(const float* __restrict__ x, const float* __restrict__ stats,
                        const float* __restrict__ gg, const float* __restrict__ gb,
                        const float* __restrict__ ss, short* __restrict__ act_t){
    __shared__ float tile[32][33];
    int n0 = blockIdx.x*32, c0 = blockIdx.y*32, b = blockIdx.z;
    int tx = threadIdx.x, ty = threadIdx.y;
    #pragma unroll
    for (int k=0;k<4;k++){
        int c = c0 + ty + k*8;
        tile[ty+k*8][tx] = x[((size_t)(b*CDIM+c))*NT + n0 + tx];
    }
    __syncthreads();
    #pragma unroll
    for (int k=0;k<4;k++){
        int c = c0 + tx, n = n0 + ty + k*8;
        float raw = tile[tx][ty+k*8];
        int gi = b*32 + (c>>4);
        float v = (raw - stats[2*gi]) * stats[2*gi+1] * gg[c] + gb[c];
        v = v * (1.f + ss[b*1024 + c]) + ss[b*1024 + 512 + c];
        act_t[((size_t)(b*NT+n))*CDIM + c] = f2bf(v * sigmoidf_(v));
    }
}

__global__ void ln_rows(const float* __restrict__ in, const float* __restrict__ g,
                        const float* __restrict__ bta, short* __restrict__ out){
    int row = blockIdx.x;
    const float* base = in + (size_t)row*CDIM;
    int t = threadIdx.x;
    float v0 = base[t], v1 = base[t+256];
    __shared__ float rs[256], rq[256];
    rs[t]=v0+v1; rq[t]=v0*v0+v1*v1; __syncthreads();
    for (int st=128; st>0; st>>=1){
        if (t<st){ rs[t]+=rs[t+st]; rq[t]+=rq[t+st]; }
        __syncthreads();
    }
    float mu = rs[0]*(1.f/512.f);
    float var = rq[0]*(1.f/512.f) - mu*mu;
    float rstd = rsqrtf(var + 1e-5f);
    out[(size_t)row*CDIM + t]     = f2bf((v0-mu)*rstd*g[t]+bta[t]);
    out[(size_t)row*CDIM + t+256] = f2bf((v1-mu)*rstd*g[t+256]+bta[t+256]);
}

__global__ void transpose_ctx(const float* __restrict__ in, short* __restrict__ out){
    __shared__ float tile[32][33];
    int m0 = blockIdx.x*32, c0 = blockIdx.y*32, b = blockIdx.z;
    int tx=threadIdx.x, ty=threadIdx.y;
    #pragma unroll
    for (int k=0;k<4;k++){
        int c = c0+ty+k*8;
        tile[ty+k*8][tx] = in[((size_t)(b*512+c))*MT + m0+tx];
    }
    __syncthreads();
    #pragma unroll
    for (int k=0;k<4;k++){
        int m = m0+ty+k*8, c = c0+tx;
        out[((size_t)(b*MT+m))*512 + c] = f2bf(tile[tx][ty+k*8]);
    }
}

__global__ void transpose_out(const float* __restrict__ in, float* __restrict__ out){
    __shared__ float tile[32][33];
    int n0 = blockIdx.x*32, c0 = blockIdx.y*32, b=blockIdx.z;
    int tx=threadIdx.x, ty=threadIdx.y;
    #pragma unroll
    for (int k=0;k<4;k++){
        int n = n0+ty+k*8;
        tile[ty+k*8][tx] = in[((size_t)(b*NT+n))*512 + c0+tx];
    }
    __syncthreads();
    #pragma unroll
    for (int k=0;k<4;k++){
        int c = c0+ty+k*8, n = n0+tx;
        out[((size_t)(b*512+c))*NT + n] = tile[tx][ty+k*8];
    }
}

// ---------------- bf16 GEMM: 128x64 tile, BK=64, GLDS staging ----------------
// grid (M/128, O/64). 2+ blocks/CU for O=512 (occupancy fix vs 128x128).
// resmode: 0 none, 1 res[row*O+col] f32, 2 res[(b*512+col)*1024+n] f32 (row=b*1024+n)
__global__ __launch_bounds__(256,2) void gemm_bb(
        const short* __restrict__ A, const short* __restrict__ W,
        const float* __restrict__ bias, const float* __restrict__ res,
        float* __restrict__ outf, short* __restrict__ outb,
        int K, int O, int ostr, int resmode){
    __shared__ short As[128*64];
    __shared__ short Bs[64*64];
    int r0 = blockIdx.x*128, o0 = blockIdx.y*64;
    int tid = threadIdx.x, w = tid>>6, lane = tid&63;
    int quad = lane>>4, lw = lane&15;
    int g_row = lane>>3, g_s = lane&7;
    int sseg = g_s ^ g_row;
    int wr = (w&1)*64, wc = (w>>1)*32;
    f32x4 acc[4][2] = {};
    for (int k0 = 0; k0 < K; k0 += 64){
        #pragma unroll
        for (int j=0;j<4;j++){
            int row = w*32 + j*8 + g_row;
            GLDS(A + (size_t)(r0+row)*K + k0 + sseg*8, As + (w*32+j*8)*64);
        }
        #pragma unroll
        for (int j=0;j<2;j++){
            int row = w*16 + j*8 + g_row;
            GLDS(W + (size_t)(o0+row)*K + k0 + sseg*8, Bs + (w*16+j*8)*64);
        }
        __syncthreads();
        bf16x8 af[4][2], bf[2][2];
        #pragma unroll
        for (int ks=0; ks<2; ks++){
            #pragma unroll
            for (int i=0;i<4;i++){
                int row = wr + i*16 + lw;
                af[i][ks] = *(const bf16x8*)&As[row*64 + (((ks*4+quad) ^ (lw&7)))*8];
            }
            #pragma unroll
            for (int j=0;j<2;j++){
                int col = wc + j*16 + lw;
                bf[j][ks] = *(const bf16x8*)&Bs[col*64 + (((ks*4+quad) ^ (lw&7)))*8];
            }
        }
        #pragma unroll
        for (int ks=0; ks<2; ks++)
            #pragma unroll
            for (int i=0;i<4;i++)
                #pragma unroll
                for (int j=0;j<2;j++)
                    acc[i][j] = __builtin_amdgcn_mfma_f32_16x16x32_bf16(af[i][ks], bf[j][ks], acc[i][j], 0, 0, 0);
        __syncthreads();
    }
    #pragma unroll
    for (int i=0;i<4;i++){
        #pragma unroll
        for (int j=0;j<2;j++){
            #pragma unroll
            for (int reg=0; reg<4; reg++){
                int row = r0 + wr + i*16 + quad*4 + reg;
                int col = o0 + wc + j*16 + lw;
                float v = acc[i][j][reg];
                if (bias) v += bias[col];
                if (resmode==1) v += res[(size_t)row*O + col];
                else if (resmode==2){
                    int b = row >> 10, n = row & 1023;
                    v += res[((size_t)(b*CDIM+col))*NT + n];
                }
                if (outf) outf[(size_t)row*ostr + col] = v;
                else      outb[(size_t)row*ostr + col] = f2bf(v);
            }
        }
    }
}

// ---------------- FF1 fused GEGLU, 128x64 tile (x2 gates), BK=64 ----------------
__global__ __launch_bounds__(256,2) void ff1_geglu_bb(
        const short* __restrict__ A, const short* __restrict__ W,
        const float* __restrict__ b1, short* __restrict__ out){
    __shared__ short As[128*64];
    __shared__ short Ba[64*64];
    __shared__ short Bg[64*64];
    int r0 = blockIdx.x*128, j0 = blockIdx.y*64;
    int tid = threadIdx.x, w = tid>>6, lane = tid&63;
    int quad = lane>>4, lw = lane&15;
    int g_row = lane>>3, g_s = lane&7;
    int sseg = g_s ^ g_row;
    int wr = (w&1)*64, wc = (w>>1)*32;
    f32x4 acca[4][2] = {}, accg[4][2] = {};
    for (int k0 = 0; k0 < 512; k0 += 64){
        #pragma unroll
        for (int j=0;j<4;j++){
            int row = w*32 + j*8 + g_row;
            GLDS(A + (size_t)(r0+row)*512 + k0 + sseg*8, As + (w*32+j*8)*64);
        }
        #pragma unroll
        for (int j=0;j<2;j++){
            int row = w*16 + j*8 + g_row;
            GLDS(W + (size_t)(j0+row)*512 + k0 + sseg*8, Ba + (w*16+j*8)*64);
            GLDS(W + (size_t)(2048+j0+row)*512 + k0 + sseg*8, Bg + (w*16+j*8)*64);
        }
        __syncthreads();
        bf16x8 af[4][2], ba[2][2], bg[2][2];
        #pragma unroll
        for (int ks=0; ks<2; ks++){
            #pragma unroll
            for (int i=0;i<4;i++){
                int row = wr + i*16 + lw;
                af[i][ks] = *(const bf16x8*)&As[row*64 + (((ks*4+quad) ^ (lw&7)))*8];
            }
            #pragma unroll
            for (int j=0;j<2;j++){
                int col = wc + j*16 + lw;
                ba[j][ks] = *(const bf16x8*)&Ba[col*64 + (((ks*4+quad) ^ (lw&7)))*8];
                bg[j][ks] = *(const bf16x8*)&Bg[col*64 + (((ks*4+quad) ^ (lw&7)))*8];
            }
        }
        #pragma unroll
        for (int ks=0; ks<2; ks++)
            #pragma unroll
            for (int i=0;i<4;i++)
                #pragma unroll
                for (int j=0;j<2;j++){
                    acca[i][j] = __builtin_amdgcn_mfma_f32_16x16x32_bf16(af[i][ks], ba[j][ks], acca[i][j], 0, 0, 0);
                    accg[i][j] = __builtin_amdgcn_mfma_f32_16x16x32_bf16(af[i][ks], bg[j][ks], accg[i][j], 0, 0, 0);
                }
        __syncthreads();
    }
    #pragma unroll
    for (int i=0;i<4;i++){
        #pragma unroll
        for (int j=0;j<2;j++){
            #pragma unroll
            for (int reg=0; reg<4; reg++){
                int row = r0 + wr + i*16 + quad*4 + reg;
                int col = j0 + wc + j*16 + lw;
                float a = acca[i][j][reg] + b1[col];
                float g = accg[i][j][reg] + b1[2048+col];
                float gl = 0.5f*g*(1.0f + erff(g*0.70710678118654752f));
                out[(size_t)row*DFFI + col] = f2bf(a*gl);
            }
        }
    }
}

// ---------------- flash attention: GLDS staging, global V^T, no-max softmax ----------------
__global__ __launch_bounds__(256) void attn_fa(
        const short* __restrict__ q, const short* __restrict__ k,
        const short* __restrict__ vt, short* __restrict__ o,
        int Nq, int Nk, int qstr, int kstr, int vtstr, float sc_log2e){
    __shared__ short Ks[64*64];
    __shared__ short Vs[64*64];
    __shared__ short QP[64*64];   // Qs (start) then Ps (loop) — both wave-local rows
    int bh = blockIdx.x & 63;
    int qt = blockIdx.x >> 6;
    int b = bh >> 3, h = bh & 7;
    int tid = threadIdx.x, w = tid>>6, lane = tid&63;
    int quad = lane>>4, lw = lane&15;
    int lrow = lane>>3, lg = (lane&7) ^ (lane>>3);
    int q0 = qt*64;

    #pragma unroll
    for (int t=0;t<2;t++){
        int row = w*16 + t*8 + lrow;
        GLDS(q + (size_t)(b*Nq + q0 + row)*qstr + h*64 + lg*8, QP + (w*16+t*8)*64);
    }
    __syncthreads();
    bf16x8 qf[2];
    {
        int r = w*16 + lw;
        qf[0] = *(const bf16x8*)&QP[r*64 + (( quad      ^ (r&7))*8)];
        qf[1] = *(const bf16x8*)&QP[r*64 + (((quad+4) ^ (r&7))*8)];
    }

    f32x4 oacc[4] = {};
    f32x4 accl = {};
    bf16x8 ones;
    #pragma unroll
    for (int i=0;i<8;i++) ones[i] = (short)0x3F80;

    int nkt = Nk >> 6;
    for (int kt = 0; kt < nkt; kt++){
        __syncthreads();
        #pragma unroll
        for (int t=0;t<2;t++){
            int row = w*16 + t*8 + lrow;
            GLDS(k  + (size_t)(b*Nk + kt*64 + row)*kstr + h*64 + lg*8, Ks + (w*16+t*8)*64);
            GLDS(vt + (size_t)(h*64 + row)*vtstr + b*Nk + kt*64 + lg*8, Vs + (w*16+t*8)*64);
        }
        __syncthreads();

        f32x4 s[4] = {};
        #pragma unroll
        for (int ct=0;ct<4;ct++){
            int r = ct*16 + lw;
            bf16x8 kf0 = *(const bf16x8*)&Ks[r*64 + (( quad      ^ (r&7))*8)];
            bf16x8 kf1 = *(const bf16x8*)&Ks[r*64 + (((quad+4) ^ (r&7))*8)];
            s[ct] = __builtin_amdgcn_mfma_f32_16x16x32_bf16(qf[0], kf0, s[ct], 0,0,0);
            s[ct] = __builtin_amdgcn_mfma_f32_16x16x32_bf16(qf[1], kf1, s[ct], 0,0,0);
        }

        #pragma unroll
        for (int ct=0;ct<4;ct++){
            int colb = (((ct+quad)&3)*16) + lw;
            #pragma unroll
            for (int r=0;r<4;r++){
                float p = exp2f(s[ct][r]*sc_log2e);
                union { float f; unsigned u; } uv; uv.f = p;
                QP[(w*16 + quad*4 + r)*64 + colb] = (short)(uv.u >> 16);
            }
        }
        __asm__ volatile("s_waitcnt lgkmcnt(0)" ::: "memory");

        bf16x8 pf[2];
        {
            int r = w*16 + lw;
            int rot = (lw>>2)&3;
            pf[0] = *(const bf16x8*)&QP[r*64 + (((    (quad>>1) + rot)&3)*16) + (quad&1)*8];
            pf[1] = *(const bf16x8*)&QP[r*64 + (((2 + (quad>>1) + rot)&3)*16) + (quad&1)*8];
        }
        accl = __builtin_amdgcn_mfma_f32_16x16x32_bf16(pf[0], ones, accl, 0,0,0);
        accl = __builtin_amdgcn_mfma_f32_16x16x32_bf16(pf[1], ones, accl, 0,0,0);
        #pragma unroll
        for (int dt=0; dt<4; dt++){
            int r = dt*16 + lw;
            bf16x8 vf0 = *(const bf16x8*)&Vs[r*64 + (( quad      ^ (r&7))*8)];
            bf16x8 vf1 = *(const bf16x8*)&Vs[r*64 + (((quad+4) ^ (r&7))*8)];
            oacc[dt] = __builtin_amdgcn_mfma_f32_16x16x32_bf16(pf[0], vf0, oacc[dt], 0,0,0);
            oacc[dt] = __builtin_amdgcn_mfma_f32_16x16x32_bf16(pf[1], vf1, oacc[dt], 0,0,0);
        }
    }
    float inv[4];
    #pragma unroll
    for (int r=0;r<4;r++) inv[r] = 1.0f/accl[r];
    #pragma unroll
    for (int dt=0; dt<4; dt++){
        #pragma unroll
        for (int r=0;r<4;r++){
            int qi = q0 + w*16 + quad*4 + r;
            o[(size_t)(b*Nq + qi)*512 + h*64 + dt*16 + lw] = f2bf(oacc[dt][r]*inv[r]);
        }
    }
}

extern "C" void kernel_launch(void* const* d_in, const int* in_sizes, int n_in,
                              void* d_out, int out_size, void* d_ws, size_t ws_size,
                              hipStream_t stream) {
    const float* x      = (const float*)d_in[0];
    const float* emb    = (const float*)d_in[1];
    const float* context= (const float*)d_in[2];
    const float* w_emb  = (const float*)d_in[3];
    const float* b_emb  = (const float*)d_in[4];
    const float* gn_g   = (const float*)d_in[5];
    const float* gn_b   = (const float*)d_in[6];
    const float* conv_w = (const float*)d_in[7];
    const float* conv_b = (const float*)d_in[8];
    const float* a1_wq  = (const float*)d_in[9];
    const float* a1_wk  = (const float*)d_in[10];
    const float* a1_wv  = (const float*)d_in[11];
    const float* a1_wo  = (const float*)d_in[12];
    const float* a1_bo  = (const float*)d_in[13];
    const float* a2_wq  = (const float*)d_in[14];
    const float* a2_wk  = (const float*)d_in[15];
    const float* a2_wv  = (const float*)d_in[16];
    const float* a2_wo  = (const float*)d_in[17];
    const float* a2_bo  = (const float*)d_in[18];
    const float* ln1_g  = (const float*)d_in[19];
    const float* ln1_b  = (const float*)d_in[20];
    const float* ln2_g  = (const float*)d_in[21];
    const float* ln2_b  = (const float*)d_in[22];
    const float* ln3_g  = (const float*)d_in[23];
    const float* ln3_b  = (const float*)d_in[24];
    const float* ff_w1  = (const float*)d_in[25];
    const float* ff_b1  = (const float*)d_in[26];
    const float* ff_w2  = (const float*)d_in[27];
    const float* ff_b2  = (const float*)d_in[28];
    float* out = (float*)d_out;

    char* base = (char*)d_ws;
    float* SS    = (float*)base;                 // 8192 f
    float* STATS = SS + 8192;                    // 512 f
    float* F0    = (float*)(base + 65536);       // [8192,512] f32 residual
    float* F1    = F0 + 4194304;
    short* WB    = (short*)(F1 + 4194304);       // bf16 weights, 5505024 shorts
    short* qkW   = WB;                           // [1024,512]: a1_wq, a1_wk
    short* vW    = WB + 524288;                  // [512,512]
    short* wo1W  = WB + 786432;
    short* a2qW  = WB + 1048576;
    short* a2kW  = WB + 1310720;
    short* a2vW  = WB + 1572864;
    short* wo2W  = WB + 1835008;
    short* ffw1W = WB + 2097152;                 // [4096,512]
    short* ffw2W = WB + 4194304;                 // [512,2048]
    short* convW = WB + 5242880;
    short* CTXb  = WB + 5505024;                 // [2048,512]
    short* L0    = CTXb + 1048576;               // [8192,512]
    short* BIG   = L0 + 4194304;                 // multi-purpose
    short* Q0    = BIG;                          // [8192,1024]: q | k
    short* VT1   = BIG + 8388608;                // [512,8192] V^T (self)
    short* AO    = BIG + 12582912;               // [8192,512]
    short* A2Q   = BIG;                          // [8192,512]
    short* K2    = BIG + 4194304;                // [2048,512]
    short* VT2   = BIG + 5242880;                // [512,2048]
    short* ACT2  = BIG;                          // [8192,2048]

    dim3 tb(32,8);
    const float SCL2E = 0.125f * 1.4426950408889634f;

    // ---- weights -> bf16 (one launch) ----
    cvt_all<<<2688,256,0,stream>>>(a1_wq,a1_wk,a1_wv,a1_wo,a2_wq,a2_wk,a2_wv,a2_wo,
                                   ff_w1,ff_w2,conv_w, WB);

    // ---- residual conv branch ----
    emb_gemm<<<32,256,0,stream>>>(emb, w_emb, b_emb, SS);
    gn_stats<<<256,256,0,stream>>>(x, STATS);
    mod_act<<<dim3(32,16,8), tb, 0, stream>>>(x, STATS, gn_g, gn_b, SS, L0);
    transpose_ctx<<<dim3(8,16,8), tb, 0, stream>>>(context, CTXb);
    gemm_bb<<<dim3(64,8),256,0,stream>>>(L0, convW, conv_b, x, F0, nullptr, 512, 512, 512, 2);  // xt0=F0

    // ---- self attention ----
    ln_rows<<<8192,256,0,stream>>>(F0, ln1_g, ln1_b, L0);
    gemm_bb<<<dim3(64,16),256,0,stream>>>(L0, qkW, nullptr, nullptr, nullptr, Q0, 512, 1024, 1024, 0);
    gemm_bb<<<dim3(4,128),256,0,stream>>>(vW, L0, nullptr, nullptr, nullptr, VT1, 512, 8192, 8192, 0); // V^T
    attn_fa<<<1024,256,0,stream>>>(Q0, Q0+512, VT1, AO, 1024, 1024, 1024, 1024, 8192, SCL2E);
    gemm_bb<<<dim3(64,8),256,0,stream>>>(AO, wo1W, a1_bo, F0, F1, nullptr, 512, 512, 512, 1);   // xt1=F1

    // ---- cross attention ----
    ln_rows<<<8192,256,0,stream>>>(F1, ln2_g, ln2_b, L0);
    gemm_bb<<<dim3(64,8),256,0,stream>>>(L0, a2qW, nullptr, nullptr, nullptr, A2Q, 512, 512, 512, 0);
    gemm_bb<<<dim3(16,8),256,0,stream>>>(CTXb, a2kW, nullptr, nullptr, nullptr, K2, 512, 512, 512, 0);
    gemm_bb<<<dim3(4,32),256,0,stream>>>(a2vW, CTXb, nullptr, nullptr, nullptr, VT2, 512, 2048, 2048, 0); // V^T
    attn_fa<<<1024,256,0,stream>>>(A2Q, K2, VT2, AO, 1024, 256, 512, 512, 2048, SCL2E);
    gemm_bb<<<dim3(64,8),256,0,stream>>>(AO, wo2W, a2_bo, F1, F0, nullptr, 512, 512, 512, 1);   // xt2=F0

    // ---- GEGLU FF ----
    ln_rows<<<8192,256,0,stream>>>(F0, ln3_g, ln3_b, L0);
    ff1_geglu_bb<<<dim3(64,32),256,0,stream>>>(L0, ffw1W, ff_b1, ACT2);
    gemm_bb<<<dim3(64,8),256,0,stream>>>(ACT2, ffw2W, ff_b2, F0, F1, nullptr, 2048, 512, 512, 1);
    transpose_out<<<dim3(32,16,8), tb, 0, stream>>>(F1, out);
}